// Round 10
// baseline (485.412 us; speedup 1.0000x reference)
//
#include <hip/hip_runtime.h>
#include <hip/hip_bf16.h>

#define NROWS 128           // B*E rows
#define NCOLS 4096          // N
#define KVAL  64
#define NEGV  (-1e30f)
#define LOG2E 1.4426950408889634f
#define LN2   0.6931471805599453f

// ESP tables, j=0 column (identically 0) NOT stored: slot j-1 holds state j.
__device__ float g_suf[(size_t)NROWS * (NCOLS + 1) * 64];
__device__ float g_pre[(size_t)NROWS * (NCOLS + 1) * 64];
__device__ float g_th [(size_t)NROWS * NCOLS];                     // theta: [m][t]
__device__ unsigned long long g_mask[(size_t)2 * NROWS * NCOLS];   // [e][m][t]

// wave-wide shift-up-by-1 via DPP wave_shr:1 (0x138); lane 0 -> 0.0f.
__device__ __forceinline__ float shr1z(float x) {
    int r = __builtin_amdgcn_update_dpp(0, __float_as_int(x), 0x138, 0xF, 0xF, true);
    return __int_as_float(r);
}
__device__ __forceinline__ float readlane_f(float v, int lane) {
    return __int_as_float(__builtin_amdgcn_readlane(__float_as_int(v), lane));
}
// fast logaddexp: max(a,b) + ln2 * log2(1 + exp2(-|a-b|*log2e))
// (bit-identical to rounds 3..9 passing table construction)
__device__ __forceinline__ float lae_fast(float a, float b) {
    float mx = fmaxf(a, b);
    float d  = fabsf(a - b);
    float e  = __builtin_amdgcn_exp2f(d * -LOG2E);
    return fmaf(__builtin_amdgcn_logf(1.0f + e), LN2, mx);
}

// DPP wave64 reductions (VALU pipe; result lands in lane 63 -> readlane).
__device__ __forceinline__ float dpp_max64(float x) {
#define MSTEP(ctrl, rmask) { int t_ = __builtin_amdgcn_update_dpp(__float_as_int(x), \
        __float_as_int(x), ctrl, rmask, 0xF, false); x = fmaxf(x, __int_as_float(t_)); }
    MSTEP(0x111, 0xF) MSTEP(0x112, 0xF) MSTEP(0x114, 0xF) MSTEP(0x118, 0xF)
    MSTEP(0x142, 0xA) MSTEP(0x143, 0xC)
#undef MSTEP
    return readlane_f(x, 63);
}
__device__ __forceinline__ float dpp_sum64(float x) {
#define SSTEP(ctrl, rmask) { int t_ = __builtin_amdgcn_update_dpp(0, \
        __float_as_int(x), ctrl, rmask, 0xF, false); x = x + __int_as_float(t_); }
    SSTEP(0x111, 0xF) SSTEP(0x112, 0xF) SSTEP(0x114, 0xF) SSTEP(0x118, 0xF)
    SSTEP(0x142, 0xA) SSTEP(0x143, 0xC)
#undef SSTEP
    return readlane_f(x, 63);
}

// scores (64,4096,2) -> g_th[m=2b+e][t]
__global__ void transpose_kernel(const float* __restrict__ scores) {
    int idx = blockIdx.x * blockDim.x + threadIdx.x;   // over 64*4096
    int b = idx >> 12, n = idx & (NCOLS - 1);
    float2 v = ((const float2*)scores)[idx];
    g_th[(size_t)(2 * b)     * NCOLS + n] = v.x;
    g_th[(size_t)(2 * b + 1) * NCOLS + n] = v.y;
}

// Pure DP, EXACT round-6/9 form (known-passing bits). One wave per chain;
// blocks [0,128): suffix (backward), [128,256): prefix (forward).
// Lane l = state j=l+1; state 0 is identically 0 (DPP zero-fill).
__global__ __launch_bounds__(64) void dp_kernel() {
    int blk = blockIdx.x;
    int l = threadIdx.x;
    bool suf = (blk < NROWS);
    int m = suf ? blk : (blk - NROWS);
    float* __restrict__ tab = (suf ? g_suf : g_pre) + (size_t)m * (NCOLS + 1) * 64;
    const float* __restrict__ th = g_th + (size_t)m * NCOLS;

    tab[(size_t)(suf ? NCOLS : 0) * 64 + l] = NEGV;    // init state row
    float s = NEGV;
    if (suf) {
        #pragma unroll 8
        for (int tt = 0; tt < NCOLS; ++tt) {
            int t = NCOLS - 1 - tt;
            float b = shr1z(s) + th[t];                // th[t] uniform -> s_load
            s = lae_fast(s, b);
            tab[(size_t)t * 64 + l] = s;
        }
    } else {
        #pragma unroll 8
        for (int t = 0; t < NCOLS; ++t) {
            float b = shr1z(s) + th[t];
            s = lae_fast(s, b);
            tab[(size_t)(t + 1) * 64 + l] = s;
        }
    }
}

// Fused mask + marg. One wave per (m, t0): S rows t0..t0+64 live in R[65] and
// feed BOTH the sampler masks (bit-identical dataflow to passing round 9) and
// the marginal LSEs (vS via register shfl instead of a second pass over g_suf).
__global__ __launch_bounds__(256) void mid_kernel(const float* __restrict__ u,
                                                  float* __restrict__ out) {
    int l = threadIdx.x & 63;
    int wid = threadIdx.x >> 6;
    int unit = blockIdx.x * 4 + wid;         // 0..8191
    int m  = unit >> 6;
    int t0 = (unit & 63) << 6;
    size_t rowbase = (size_t)m * (NCOLS + 1) * 64;
    const float* __restrict__ S = g_suf + rowbase;
    const float* __restrict__ P = g_pre + rowbase;
    const float* __restrict__ trow = g_th + (size_t)m * NCOLS;
    const float* __restrict__ u0 = u + (size_t)m * NCOLS;             // ens 0
    const float* __restrict__ u1 = u + (size_t)(NROWS + m) * NCOLS;   // ens 1

    float R[65];                             // S rows t0..t0+64, lane l = slot l
    #pragma unroll
    for (int j = 0; j <= 64; ++j) R[j] = S[(size_t)(t0 + j) * 64 + l];

    float den_full = P[(size_t)NCOLS * 64 + 63];     // log E_k(full row), uniform

    unsigned long long acc0 = 0, acc1 = 0;   // lane ss <- masks of step t0+ss
    float mres = 0.0f;                       // lane ss <- marg of element t0+ss
    #pragma unroll
    for (int ss = 0; ss < 64; ++ss) {
        int t = t0 + ss;
        // ---- sampler mask (op-for-op identical to passing round-9 kernel)
        float num = shr1z(R[ss + 1]);        // row t+1, state l (lane0 -> 0)
        float den = R[ss];                   // row t, state l+1
        float p = __builtin_amdgcn_exp2f(((num + trow[t]) - den) * LOG2E);
        unsigned long long b0 = __ballot(u0[t] < p);
        unsigned long long b1 = __ballot(u1[t] < p);
        acc0 = (l == ss) ? b0 : acc0;
        acc1 = (l == ss) ? b1 : acc1;
        // ---- marginal (output 1, 2e-2 tol): v_l = P[t][state l] + S[t+1][state 63-l]
        float vP = (l == 0)  ? 0.0f : P[(size_t)t * 64 + (l - 1)];
        float vS = (l == 63) ? 0.0f : __shfl(R[ss + 1], 62 - l);   // register copy
        float v = vP + vS;
        float M = dpp_max64(v);
        float sum = dpp_sum64(__builtin_amdgcn_exp2f((v - M) * LOG2E));
        float lse = fmaf(__builtin_amdgcn_logf(sum), LN2, M);
        float mg = __builtin_amdgcn_exp2f((trow[t] + lse - den_full) * LOG2E);
        mres = (l == ss) ? mg : mres;
    }
    g_mask[(size_t)m * NCOLS + t0 + l] = acc0;               // coalesced 512B
    g_mask[(size_t)(NROWS + m) * NCOLS + t0 + l] = acc1;
    size_t obase = (size_t)2 * 64 * NCOLS * 2;
    out[obase + ((size_t)(m >> 1) * NCOLS + (t0 + l)) * 2 + (m & 1)] = mres;
}

// Sampler scan: masks broadcast via v_readlane -> SGPR pair; the r-carried
// chain is pure SALU (s_lshr_b64/s_and/s_sub), no DS ops.
__global__ __launch_bounds__(64) void scan_kernel(float* __restrict__ out) {
    int chain = blockIdx.x;              // 0..255
    int l = threadIdx.x;
    int tens = chain >> 7;
    int m = chain & (NROWS - 1);
    const unsigned long long* __restrict__ gm =
        g_mask + ((size_t)tens * NROWS + m) * NCOLS;
    float* __restrict__ orow = out + (((size_t)tens * 64 + (m >> 1)) * NCOLS) * 2 + (m & 1);

    int r = KVAL;
    unsigned long long tile = gm[l];                 // coalesced 512B tile
    for (int t0 = 0; t0 < NCOLS; t0 += 64) {
        unsigned long long next = (t0 + 64 < NCOLS) ? gm[t0 + 64 + l] : 0ULL;
        unsigned int tlo = (unsigned int)tile;
        unsigned int thi = (unsigned int)(tile >> 32);
        int myinc = 0;
        #pragma unroll
        for (int ss = 0; ss < 64; ++ss) {
            unsigned int slo = (unsigned int)__builtin_amdgcn_readlane((int)tlo, ss);
            unsigned int shi = (unsigned int)__builtin_amdgcn_readlane((int)thi, ss);
            unsigned long long msk = ((unsigned long long)shi << 32) | slo;
            int inc = (r > 0) ? (int)((msk >> (r - 1)) & 1ULL) : 0;
            myinc = (ss == l) ? inc : myinc;
            r -= inc;
        }
        orow[(size_t)(t0 + l) * 2] = (float)myinc;
        tile = next;
    }
}

extern "C" void kernel_launch(void* const* d_in, const int* in_sizes, int n_in,
                              void* d_out, int out_size, void* d_ws, size_t ws_size,
                              hipStream_t stream) {
    const float* scores = (const float*)d_in[0];   // (64, 4096, 2) f32
    const float* u      = (const float*)d_in[1];   // (2, 128, 4096) f32
    float* out = (float*)d_out;

    transpose_kernel<<<(64 * NCOLS) / 256, 256, 0, stream>>>(scores);
    dp_kernel<<<2 * NROWS, 64, 0, stream>>>();
    mid_kernel<<<2048, 256, 0, stream>>>(u, out);
    scan_kernel<<<2 * NROWS, 64, 0, stream>>>(out);
}

// Round 11
// 406.003 us; speedup vs baseline: 1.1956x; 1.1956x over previous
//
#include <hip/hip_runtime.h>
#include <hip/hip_bf16.h>

#define NROWS 128           // B*E rows
#define NCOLS 4096          // N
#define KVAL  64
#define NEGV  (-1e30f)
#define LOG2E 1.4426950408889634f
#define LN2   0.6931471805599453f

// ESP tables, j=0 column (identically 0) NOT stored: slot j-1 holds state j.
__device__ float g_suf[(size_t)NROWS * (NCOLS + 1) * 64];
__device__ float g_pre[(size_t)NROWS * (NCOLS + 1) * 64];
__device__ float g_th [(size_t)NROWS * NCOLS];                     // theta: [m][t]
__device__ unsigned long long g_mask[(size_t)2 * NROWS * NCOLS];   // [e][m][t]

// wave-wide shift-up-by-1 via DPP wave_shr:1 (0x138); lane 0 -> 0.0f.
__device__ __forceinline__ float shr1z(float x) {
    int r = __builtin_amdgcn_update_dpp(0, __float_as_int(x), 0x138, 0xF, 0xF, true);
    return __int_as_float(r);
}
__device__ __forceinline__ float readlane_f(float v, int lane) {
    return __int_as_float(__builtin_amdgcn_readlane(__float_as_int(v), lane));
}
// fast logaddexp: max(a,b) + ln2 * log2(1 + exp2(-|a-b|*log2e))
// (bit-identical to rounds 3..10 passing table construction)
__device__ __forceinline__ float lae_fast(float a, float b) {
    float mx = fmaxf(a, b);
    float d  = fabsf(a - b);
    float e  = __builtin_amdgcn_exp2f(d * -LOG2E);
    return fmaf(__builtin_amdgcn_logf(1.0f + e), LN2, mx);
}

// DPP wave64 sum reduction (VALU pipe; result broadcast from lane 63).
__device__ __forceinline__ float dpp_sum64(float x) {
#define SSTEP(ctrl, rmask) { int t_ = __builtin_amdgcn_update_dpp(0, \
        __float_as_int(x), ctrl, rmask, 0xF, false); x = x + __int_as_float(t_); }
    SSTEP(0x111, 0xF) SSTEP(0x112, 0xF) SSTEP(0x114, 0xF) SSTEP(0x118, 0xF)
    SSTEP(0x142, 0xA) SSTEP(0x143, 0xC)
#undef SSTEP
    return readlane_f(x, 63);
}

// scores (64,4096,2) -> g_th[m=2b+e][t]
__global__ void transpose_kernel(const float* __restrict__ scores) {
    int idx = blockIdx.x * blockDim.x + threadIdx.x;   // over 64*4096
    int b = idx >> 12, n = idx & (NCOLS - 1);
    float2 v = ((const float2*)scores)[idx];
    g_th[(size_t)(2 * b)     * NCOLS + n] = v.x;
    g_th[(size_t)(2 * b + 1) * NCOLS + n] = v.y;
}

// DP, carry chain EXACTLY as rounds 6/9/10 (known-passing bits). Theta is
// delivered via a double-buffered coalesced register tile + v_readlane
// broadcast (round-3 delivery, ~135us) instead of per-step s_loads (~198us).
// Values are bit-identical; only the delivery path changes.
__global__ __launch_bounds__(64) void dp_kernel() {
    int blk = blockIdx.x;
    int l = threadIdx.x;
    bool suf = (blk < NROWS);
    int m = suf ? blk : (blk - NROWS);
    float* __restrict__ tab = (suf ? g_suf : g_pre) + (size_t)m * (NCOLS + 1) * 64;
    const float* __restrict__ th = g_th + (size_t)m * NCOLS;

    tab[(size_t)(suf ? NCOLS : 0) * 64 + l] = NEGV;    // init state row
    float s = NEGV;
    if (suf) {
        float tile = th[NCOLS - 64 + l];               // coalesced 256B tile
        for (int t0 = NCOLS - 64; t0 >= 0; t0 -= 64) {
            float nxt = (t0 >= 64) ? th[t0 - 64 + l] : 0.0f;   // prefetch, off-chain
            #pragma unroll
            for (int ss = 63; ss >= 0; --ss) {
                float tht = readlane_f(tile, ss);      // broadcast, no lgkm wait
                float b = shr1z(s) + tht;
                s = lae_fast(s, b);
                tab[(size_t)(t0 + ss) * 64 + l] = s;
            }
            tile = nxt;
        }
    } else {
        float tile = th[l];
        for (int t0 = 0; t0 < NCOLS; t0 += 64) {
            float nxt = (t0 + 64 < NCOLS) ? th[t0 + 64 + l] : 0.0f;
            #pragma unroll
            for (int ss = 0; ss < 64; ++ss) {
                float tht = readlane_f(tile, ss);
                float b = shr1z(s) + tht;
                s = lae_fast(s, b);
                tab[(size_t)(t0 + ss + 1) * 64 + l] = s;
            }
            tile = nxt;
        }
    }
}

// Sampler ballot masks (round-9 form, bit-identical). One wave per (m,t0).
__global__ __launch_bounds__(256) void mask_kernel(const float* __restrict__ u) {
    int l = threadIdx.x & 63;
    int wid = threadIdx.x >> 6;
    int unit = blockIdx.x * 4 + wid;         // 0..8191
    int m  = unit >> 6;
    int t0 = (unit & 63) << 6;
    const float* __restrict__ S = g_suf + (size_t)m * (NCOLS + 1) * 64;
    const float* __restrict__ trow = g_th + (size_t)m * NCOLS;
    const float* __restrict__ u0 = u + (size_t)m * NCOLS;             // ens 0
    const float* __restrict__ u1 = u + (size_t)(NROWS + m) * NCOLS;   // ens 1

    float R[65];                             // S rows t0..t0+64, lane l = slot l
    #pragma unroll
    for (int j = 0; j <= 64; ++j) R[j] = S[(size_t)(t0 + j) * 64 + l];

    unsigned long long acc0 = 0, acc1 = 0;   // lane ss <- masks of step t0+ss
    #pragma unroll
    for (int ss = 0; ss < 64; ++ss) {
        int t = t0 + ss;
        float num = shr1z(R[ss + 1]);        // row t+1, state l (lane0 -> 0)
        float den = R[ss];                   // row t, state l+1
        float p = __builtin_amdgcn_exp2f(((num + trow[t]) - den) * LOG2E);
        unsigned long long b0 = __ballot(u0[t] < p);
        unsigned long long b1 = __ballot(u1[t] < p);
        acc0 = (l == ss) ? b0 : acc0;
        acc1 = (l == ss) ? b1 : acc1;
    }
    g_mask[(size_t)m * NCOLS + t0 + l] = acc0;               // coalesced 512B
    g_mask[(size_t)(NROWS + m) * NCOLS + t0 + l] = acc1;
}

// Marginals via direct normalized sum: every term P[i][a]+S[i+1][63-a] is
// <= den_full - theta_i (marginal <= 1), so normalizing by that upper bound
// gives marg = sum_a exp(vP + vS + theta_i - den_full) with all terms in
// [0,1] -- no max reduction, no log, no final exp. Output 1 only (2e-2 tol).
__global__ __launch_bounds__(256) void marg_kernel(float* __restrict__ out) {
    int l = threadIdx.x & 63;
    int wid = threadIdx.x >> 6;
    int unit = blockIdx.x * 4 + wid;         // 0..8191
    int m  = unit >> 6;
    int t0 = (unit & 63) << 6;
    size_t rowbase = (size_t)m * (NCOLS + 1) * 64;
    const float* __restrict__ P = g_pre + rowbase;
    const float* __restrict__ S = g_suf + rowbase;
    const float* __restrict__ trow = g_th + (size_t)m * NCOLS;
    float den_full = P[(size_t)NCOLS * 64 + 63];     // log E_k(full row), uniform

    float mres = 0.0f;                       // lane j <- marg of element t0+j
    #pragma unroll 4
    for (int j = 0; j < 64; ++j) {
        int i = t0 + j;
        float vP = (l == 0)  ? 0.0f : P[(size_t)i * 64 + (l - 1)];        // state l
        float vS = (l == 63) ? 0.0f : S[(size_t)(i + 1) * 64 + (62 - l)]; // state 63-l
        float c  = trow[i] - den_full;                                    // uniform
        float term = __builtin_amdgcn_exp2f((vP + vS + c) * LOG2E);       // <= 1
        float mg = dpp_sum64(term);
        mres = (l == j) ? mg : mres;
    }
    size_t obase = (size_t)2 * 64 * NCOLS * 2;
    out[obase + ((size_t)(m >> 1) * NCOLS + (t0 + l)) * 2 + (m & 1)] = mres;
}

// Sampler scan: masks broadcast via v_readlane -> SGPR pair; the r-carried
// chain is pure SALU (s_lshr_b64/s_and/s_sub), no DS ops.
__global__ __launch_bounds__(64) void scan_kernel(float* __restrict__ out) {
    int chain = blockIdx.x;              // 0..255
    int l = threadIdx.x;
    int tens = chain >> 7;
    int m = chain & (NROWS - 1);
    const unsigned long long* __restrict__ gm =
        g_mask + ((size_t)tens * NROWS + m) * NCOLS;
    float* __restrict__ orow = out + (((size_t)tens * 64 + (m >> 1)) * NCOLS) * 2 + (m & 1);

    int r = KVAL;
    unsigned long long tile = gm[l];                 // coalesced 512B tile
    for (int t0 = 0; t0 < NCOLS; t0 += 64) {
        unsigned long long next = (t0 + 64 < NCOLS) ? gm[t0 + 64 + l] : 0ULL;
        unsigned int tlo = (unsigned int)tile;
        unsigned int thi = (unsigned int)(tile >> 32);
        int myinc = 0;
        #pragma unroll
        for (int ss = 0; ss < 64; ++ss) {
            unsigned int slo = (unsigned int)__builtin_amdgcn_readlane((int)tlo, ss);
            unsigned int shi = (unsigned int)__builtin_amdgcn_readlane((int)thi, ss);
            unsigned long long msk = ((unsigned long long)shi << 32) | slo;
            int inc = (r > 0) ? (int)((msk >> (r - 1)) & 1ULL) : 0;
            myinc = (ss == l) ? inc : myinc;
            r -= inc;
        }
        orow[(size_t)(t0 + l) * 2] = (float)myinc;
        tile = next;
    }
}

extern "C" void kernel_launch(void* const* d_in, const int* in_sizes, int n_in,
                              void* d_out, int out_size, void* d_ws, size_t ws_size,
                              hipStream_t stream) {
    const float* scores = (const float*)d_in[0];   // (64, 4096, 2) f32
    const float* u      = (const float*)d_in[1];   // (2, 128, 4096) f32
    float* out = (float*)d_out;

    transpose_kernel<<<(64 * NCOLS) / 256, 256, 0, stream>>>(scores);
    dp_kernel<<<2 * NROWS, 64, 0, stream>>>();
    mask_kernel<<<2048, 256, 0, stream>>>(u);
    marg_kernel<<<2048, 256, 0, stream>>>(out);
    scan_kernel<<<2 * NROWS, 64, 0, stream>>>(out);
}

// Round 12
// 282.694 us; speedup vs baseline: 1.7171x; 1.4362x over previous
//
#include <hip/hip_runtime.h>
#include <hip/hip_bf16.h>

#define NROWS 128           // B*E rows
#define NCOLS 4096          // N
#define KVAL  64
#define NEGV  (-1e30f)
#define LOG2E 1.4426950408889634f
#define LN2   0.6931471805599453f

// ESP tables, j=0 column (identically 0) NOT stored: slot j-1 holds state j.
__device__ float g_suf[(size_t)NROWS * (NCOLS + 1) * 64];
__device__ float g_pre[(size_t)NROWS * (NCOLS + 1) * 64];
__device__ float g_th [(size_t)NROWS * NCOLS];                     // theta: [m][t]
__device__ unsigned long long g_mask[(size_t)2 * NROWS * NCOLS];   // [chain][t]
__device__ unsigned char g_map  [(size_t)2 * NROWS * 64 * 64];     // [chain][blk][entry-1]
__device__ unsigned char g_entry[(size_t)2 * NROWS * 64];          // [chain][blk]

// wave-wide shift-up-by-1 via DPP wave_shr:1 (0x138); lane 0 -> 0.0f.
__device__ __forceinline__ float shr1z(float x) {
    int r = __builtin_amdgcn_update_dpp(0, __float_as_int(x), 0x138, 0xF, 0xF, true);
    return __int_as_float(r);
}
__device__ __forceinline__ float readlane_f(float v, int lane) {
    return __int_as_float(__builtin_amdgcn_readlane(__float_as_int(v), lane));
}
// fast logaddexp: max(a,b) + ln2 * log2(1 + exp2(-|a-b|*log2e))
// (bit-identical to rounds 3..11 passing table construction)
__device__ __forceinline__ float lae_fast(float a, float b) {
    float mx = fmaxf(a, b);
    float d  = fabsf(a - b);
    float e  = __builtin_amdgcn_exp2f(d * -LOG2E);
    return fmaf(__builtin_amdgcn_logf(1.0f + e), LN2, mx);
}

// DPP wave64 sum reduction (VALU pipe; result broadcast from lane 63).
__device__ __forceinline__ float dpp_sum64(float x) {
#define SSTEP(ctrl, rmask) { int t_ = __builtin_amdgcn_update_dpp(0, \
        __float_as_int(x), ctrl, rmask, 0xF, false); x = x + __int_as_float(t_); }
    SSTEP(0x111, 0xF) SSTEP(0x112, 0xF) SSTEP(0x114, 0xF) SSTEP(0x118, 0xF)
    SSTEP(0x142, 0xA) SSTEP(0x143, 0xC)
#undef SSTEP
    return readlane_f(x, 63);
}

// scores (64,4096,2) -> g_th[m=2b+e][t]
__global__ void transpose_kernel(const float* __restrict__ scores) {
    int idx = blockIdx.x * blockDim.x + threadIdx.x;   // over 64*4096
    int b = idx >> 12, n = idx & (NCOLS - 1);
    float2 v = ((const float2*)scores)[idx];
    g_th[(size_t)(2 * b)     * NCOLS + n] = v.x;
    g_th[(size_t)(2 * b + 1) * NCOLS + n] = v.y;
}

// DP, round-11 form (passing): carry chain bits identical to rounds 6..11;
// theta via double-buffered register tile + v_readlane broadcast.
__global__ __launch_bounds__(64) void dp_kernel() {
    int blk = blockIdx.x;
    int l = threadIdx.x;
    bool suf = (blk < NROWS);
    int m = suf ? blk : (blk - NROWS);
    float* __restrict__ tab = (suf ? g_suf : g_pre) + (size_t)m * (NCOLS + 1) * 64;
    const float* __restrict__ th = g_th + (size_t)m * NCOLS;

    tab[(size_t)(suf ? NCOLS : 0) * 64 + l] = NEGV;    // init state row
    float s = NEGV;
    if (suf) {
        float tile = th[NCOLS - 64 + l];               // coalesced 256B tile
        for (int t0 = NCOLS - 64; t0 >= 0; t0 -= 64) {
            float nxt = (t0 >= 64) ? th[t0 - 64 + l] : 0.0f;   // prefetch, off-chain
            #pragma unroll
            for (int ss = 63; ss >= 0; --ss) {
                float tht = readlane_f(tile, ss);      // broadcast, no lgkm wait
                float b = shr1z(s) + tht;
                s = lae_fast(s, b);
                tab[(size_t)(t0 + ss) * 64 + l] = s;
            }
            tile = nxt;
        }
    } else {
        float tile = th[l];
        for (int t0 = 0; t0 < NCOLS; t0 += 64) {
            float nxt = (t0 + 64 < NCOLS) ? th[t0 + 64 + l] : 0.0f;
            #pragma unroll
            for (int ss = 0; ss < 64; ++ss) {
                float tht = readlane_f(tile, ss);
                float b = shr1z(s) + tht;
                s = lae_fast(s, b);
                tab[(size_t)(t0 + ss + 1) * 64 + l] = s;
            }
            tile = nxt;
        }
    }
}

// Sampler ballot masks (round-9/11 form, bit-identical). One wave per (m,t0).
__global__ __launch_bounds__(256) void mask_kernel(const float* __restrict__ u) {
    int l = threadIdx.x & 63;
    int wid = threadIdx.x >> 6;
    int unit = blockIdx.x * 4 + wid;         // 0..8191
    int m  = unit >> 6;
    int t0 = (unit & 63) << 6;
    const float* __restrict__ S = g_suf + (size_t)m * (NCOLS + 1) * 64;
    const float* __restrict__ trow = g_th + (size_t)m * NCOLS;
    const float* __restrict__ u0 = u + (size_t)m * NCOLS;             // ens 0
    const float* __restrict__ u1 = u + (size_t)(NROWS + m) * NCOLS;   // ens 1

    float R[65];                             // S rows t0..t0+64, lane l = slot l
    #pragma unroll
    for (int j = 0; j <= 64; ++j) R[j] = S[(size_t)(t0 + j) * 64 + l];

    unsigned long long acc0 = 0, acc1 = 0;   // lane ss <- masks of step t0+ss
    #pragma unroll
    for (int ss = 0; ss < 64; ++ss) {
        int t = t0 + ss;
        float num = shr1z(R[ss + 1]);        // row t+1, state l (lane0 -> 0)
        float den = R[ss];                   // row t, state l+1
        float p = __builtin_amdgcn_exp2f(((num + trow[t]) - den) * LOG2E);
        unsigned long long b0 = __ballot(u0[t] < p);
        unsigned long long b1 = __ballot(u1[t] < p);
        acc0 = (l == ss) ? b0 : acc0;
        acc1 = (l == ss) ? b1 : acc1;
    }
    g_mask[(size_t)m * NCOLS + t0 + l] = acc0;               // coalesced 512B
    g_mask[(size_t)(NROWS + m) * NCOLS + t0 + l] = acc1;
}

// Marginals via direct normalized sum (round-11 form, passing).
__global__ __launch_bounds__(256) void marg_kernel(float* __restrict__ out) {
    int l = threadIdx.x & 63;
    int wid = threadIdx.x >> 6;
    int unit = blockIdx.x * 4 + wid;         // 0..8191
    int m  = unit >> 6;
    int t0 = (unit & 63) << 6;
    size_t rowbase = (size_t)m * (NCOLS + 1) * 64;
    const float* __restrict__ P = g_pre + rowbase;
    const float* __restrict__ S = g_suf + rowbase;
    const float* __restrict__ trow = g_th + (size_t)m * NCOLS;
    float den_full = P[(size_t)NCOLS * 64 + 63];     // log E_k(full row), uniform

    float mres = 0.0f;                       // lane j <- marg of element t0+j
    #pragma unroll 4
    for (int j = 0; j < 64; ++j) {
        int i = t0 + j;
        float vP = (l == 0)  ? 0.0f : P[(size_t)i * 64 + (l - 1)];        // state l
        float vS = (l == 63) ? 0.0f : S[(size_t)(i + 1) * 64 + (62 - l)]; // state 63-l
        float c  = trow[i] - den_full;                                    // uniform
        float term = __builtin_amdgcn_exp2f((vP + vS + c) * LOG2E);       // <= 1
        float mg = dpp_sum64(term);
        mres = (l == j) ? mg : mres;
    }
    size_t obase = (size_t)2 * 64 * NCOLS * 2;
    out[obase + ((size_t)(m >> 1) * NCOLS + (t0 + l)) * 2 + (m & 1)] = mres;
}

// ---- scan phase A: per (chain, 64-step block), compute the block's exact
// transition map. Lane l walks entry state r = l+1 (state 0 is absorbing).
__global__ __launch_bounds__(256) void scanA_kernel() {
    int l = threadIdx.x & 63;
    int wid = threadIdx.x >> 6;
    int unit = blockIdx.x * 4 + wid;         // 0..16383
    int c = unit >> 6;                       // chain
    int b = unit & 63;                       // block
    const unsigned long long* __restrict__ gm = g_mask + (size_t)c * NCOLS + b * 64;
    unsigned long long tile = gm[l];         // lane ss = mask of step b*64+ss
    unsigned int tlo = (unsigned int)tile;
    unsigned int thi = (unsigned int)(tile >> 32);
    int r = l + 1;                           // entry state for this lane
    #pragma unroll
    for (int ss = 0; ss < 64; ++ss) {
        unsigned int slo = (unsigned int)__builtin_amdgcn_readlane((int)tlo, ss);
        unsigned int shi = (unsigned int)__builtin_amdgcn_readlane((int)thi, ss);
        unsigned long long msk = ((unsigned long long)shi << 32) | slo;
        int inc = (r > 0) ? (int)((msk >> (r - 1)) & 1ULL) : 0;
        r -= inc;
    }
    g_map[((size_t)c * 64 + b) * 64 + l] = (unsigned char)r;   // coalesced 64B
}

// ---- scan phase B: compose the 64 block maps per chain (lane = chain).
__global__ __launch_bounds__(256) void scanB_kernel() {
    int c = threadIdx.x;                     // 0..255, single block
    int r = KVAL;
    for (int b = 0; b < 64; ++b) {
        g_entry[(size_t)c * 64 + b] = (unsigned char)r;
        int nxt = g_map[((size_t)c * 64 + b) * 64 + (r - 1)];
        r = (r > 0) ? nxt : 0;
    }
}

// ---- scan phase C: re-walk each block with its known entry r (all lanes
// redundant, identical to the passing sequential inner loop) and emit bits.
__global__ __launch_bounds__(256) void scanC_kernel(float* __restrict__ out) {
    int l = threadIdx.x & 63;
    int wid = threadIdx.x >> 6;
    int unit = blockIdx.x * 4 + wid;         // 0..16383
    int c = unit >> 6;
    int b = unit & 63;
    int tens = c >> 7;
    int m = c & (NROWS - 1);
    const unsigned long long* __restrict__ gm = g_mask + (size_t)c * NCOLS + b * 64;
    float* __restrict__ orow = out + (((size_t)tens * 64 + (m >> 1)) * NCOLS) * 2 + (m & 1);

    unsigned long long tile = gm[l];
    unsigned int tlo = (unsigned int)tile;
    unsigned int thi = (unsigned int)(tile >> 32);
    int r = g_entry[(size_t)c * 64 + b];     // uniform
    int myinc = 0;
    #pragma unroll
    for (int ss = 0; ss < 64; ++ss) {
        unsigned int slo = (unsigned int)__builtin_amdgcn_readlane((int)tlo, ss);
        unsigned int shi = (unsigned int)__builtin_amdgcn_readlane((int)thi, ss);
        unsigned long long msk = ((unsigned long long)shi << 32) | slo;
        int inc = (r > 0) ? (int)((msk >> (r - 1)) & 1ULL) : 0;
        myinc = (ss == l) ? inc : myinc;
        r -= inc;
    }
    orow[(size_t)(b * 64 + l) * 2] = (float)myinc;
}

extern "C" void kernel_launch(void* const* d_in, const int* in_sizes, int n_in,
                              void* d_out, int out_size, void* d_ws, size_t ws_size,
                              hipStream_t stream) {
    const float* scores = (const float*)d_in[0];   // (64, 4096, 2) f32
    const float* u      = (const float*)d_in[1];   // (2, 128, 4096) f32
    float* out = (float*)d_out;

    transpose_kernel<<<(64 * NCOLS) / 256, 256, 0, stream>>>(scores);
    dp_kernel<<<2 * NROWS, 64, 0, stream>>>();
    mask_kernel<<<2048, 256, 0, stream>>>(u);
    marg_kernel<<<2048, 256, 0, stream>>>(out);
    scanA_kernel<<<4096, 256, 0, stream>>>();
    scanB_kernel<<<1, 256, 0, stream>>>();
    scanC_kernel<<<4096, 256, 0, stream>>>(out);
}

// Round 13
// 273.398 us; speedup vs baseline: 1.7755x; 1.0340x over previous
//
#include <hip/hip_runtime.h>
#include <hip/hip_bf16.h>

#define NROWS 128           // B*E rows
#define NCOLS 4096          // N
#define KVAL  64
#define NEGV  (-1e30f)
#define LOG2E 1.4426950408889634f
#define LN2   0.6931471805599453f

// ESP tables, j=0 column (identically 0) NOT stored: slot j-1 holds state j.
__device__ float g_suf[(size_t)NROWS * (NCOLS + 1) * 64];
__device__ float g_pre[(size_t)NROWS * (NCOLS + 1) * 64];
__device__ unsigned long long g_mask[(size_t)2 * NROWS * NCOLS];   // [chain][t]
__device__ unsigned char g_map  [(size_t)2 * NROWS * 64 * 64];     // [chain][blk][entry-1]
__device__ unsigned char g_entry[(size_t)2 * NROWS * 64];          // [chain][blk]

// wave-wide shift-up-by-1 via DPP wave_shr:1 (0x138); lane 0 -> 0.0f.
__device__ __forceinline__ float shr1z(float x) {
    int r = __builtin_amdgcn_update_dpp(0, __float_as_int(x), 0x138, 0xF, 0xF, true);
    return __int_as_float(r);
}
__device__ __forceinline__ float readlane_f(float v, int lane) {
    return __int_as_float(__builtin_amdgcn_readlane(__float_as_int(v), lane));
}
// fast logaddexp: max(a,b) + ln2 * log2(1 + exp2(-|a-b|*log2e))
// (bit-identical to rounds 3..12 passing table construction)
__device__ __forceinline__ float lae_fast(float a, float b) {
    float mx = fmaxf(a, b);
    float d  = fabsf(a - b);
    float e  = __builtin_amdgcn_exp2f(d * -LOG2E);
    return fmaf(__builtin_amdgcn_logf(1.0f + e), LN2, mx);
}

// DPP wave64 sum reduction (VALU pipe; result broadcast from lane 63).
__device__ __forceinline__ float dpp_sum64(float x) {
#define SSTEP(ctrl, rmask) { int t_ = __builtin_amdgcn_update_dpp(0, \
        __float_as_int(x), ctrl, rmask, 0xF, false); x = x + __int_as_float(t_); }
    SSTEP(0x111, 0xF) SSTEP(0x112, 0xF) SSTEP(0x114, 0xF) SSTEP(0x118, 0xF)
    SSTEP(0x142, 0xA) SSTEP(0x143, 0xC)
#undef SSTEP
    return readlane_f(x, 63);
}

// DP, round-11/12 carry chain (bit-identical); theta tiles loaded directly
// from scores (stride-8B coalesced, off-chain) -- no transpose pass needed.
__global__ __launch_bounds__(64) void dp_kernel(const float* __restrict__ scores) {
    int blk = blockIdx.x;
    int l = threadIdx.x;
    bool suf = (blk < NROWS);
    int m = suf ? blk : (blk - NROWS);
    float* __restrict__ tab = (suf ? g_suf : g_pre) + (size_t)m * (NCOLS + 1) * 64;
    const float* __restrict__ srow = scores + (size_t)(m >> 1) * (NCOLS * 2) + (m & 1);

    tab[(size_t)(suf ? NCOLS : 0) * 64 + l] = NEGV;    // init state row
    float s = NEGV;
    if (suf) {
        float tile = srow[(size_t)(NCOLS - 64 + l) * 2];       // theta tile
        for (int t0 = NCOLS - 64; t0 >= 0; t0 -= 64) {
            float nxt = (t0 >= 64) ? srow[(size_t)(t0 - 64 + l) * 2] : 0.0f;
            #pragma unroll
            for (int ss = 63; ss >= 0; --ss) {
                float tht = readlane_f(tile, ss);      // broadcast, off-chain
                float b = shr1z(s) + tht;
                s = lae_fast(s, b);
                tab[(size_t)(t0 + ss) * 64 + l] = s;
            }
            tile = nxt;
        }
    } else {
        float tile = srow[(size_t)l * 2];
        for (int t0 = 0; t0 < NCOLS; t0 += 64) {
            float nxt = (t0 + 64 < NCOLS) ? srow[(size_t)(t0 + 64 + l) * 2] : 0.0f;
            #pragma unroll
            for (int ss = 0; ss < 64; ++ss) {
                float tht = readlane_f(tile, ss);
                float b = shr1z(s) + tht;
                s = lae_fast(s, b);
                tab[(size_t)(t0 + ss + 1) * 64 + l] = s;
            }
            tile = nxt;
        }
    }
}

// Sampler ballot masks (round-12 dataflow, bit-identical) + FUSED scanA:
// after the ballot loop, lane ss already holds step t0+ss's mask, so the
// block transition map is computed in-register (integer-exact) and stored.
__global__ __launch_bounds__(256) void maskA_kernel(const float* __restrict__ scores,
                                                    const float* __restrict__ u) {
    int l = threadIdx.x & 63;
    int wid = threadIdx.x >> 6;
    int unit = blockIdx.x * 4 + wid;         // 0..8191
    int m  = unit >> 6;
    int b  = unit & 63;                      // t-block index
    int t0 = b << 6;
    const float* __restrict__ S = g_suf + (size_t)m * (NCOLS + 1) * 64;
    const float* __restrict__ srow = scores + (size_t)(m >> 1) * (NCOLS * 2) + (m & 1);
    const float* __restrict__ u0 = u + (size_t)m * NCOLS;             // ens 0
    const float* __restrict__ u1 = u + (size_t)(NROWS + m) * NCOLS;   // ens 1

    float R[65];                             // S rows t0..t0+64, lane l = slot l
    #pragma unroll
    for (int j = 0; j <= 64; ++j) R[j] = S[(size_t)(t0 + j) * 64 + l];

    unsigned long long acc0 = 0, acc1 = 0;   // lane ss <- masks of step t0+ss
    #pragma unroll
    for (int ss = 0; ss < 64; ++ss) {
        int t = t0 + ss;
        float num = shr1z(R[ss + 1]);        // row t+1, state l (lane0 -> 0)
        float den = R[ss];                   // row t, state l+1
        float tht = srow[(size_t)t * 2];     // wave-uniform theta
        float p = __builtin_amdgcn_exp2f(((num + tht) - den) * LOG2E);
        unsigned long long b0 = __ballot(u0[t] < p);
        unsigned long long b1 = __ballot(u1[t] < p);
        acc0 = (l == ss) ? b0 : acc0;
        acc1 = (l == ss) ? b1 : acc1;
    }
    g_mask[(size_t)m * NCOLS + t0 + l] = acc0;               // coalesced 512B
    g_mask[(size_t)(NROWS + m) * NCOLS + t0 + l] = acc1;

    // ---- fused scanA: walk both ensembles' transition maps from registers.
    unsigned int a0lo = (unsigned int)acc0, a0hi = (unsigned int)(acc0 >> 32);
    unsigned int a1lo = (unsigned int)acc1, a1hi = (unsigned int)(acc1 >> 32);
    int r0 = l + 1, r1 = l + 1;              // entry state for this lane
    #pragma unroll
    for (int ss = 0; ss < 64; ++ss) {
        unsigned int m0lo = (unsigned int)__builtin_amdgcn_readlane((int)a0lo, ss);
        unsigned int m0hi = (unsigned int)__builtin_amdgcn_readlane((int)a0hi, ss);
        unsigned int m1lo = (unsigned int)__builtin_amdgcn_readlane((int)a1lo, ss);
        unsigned int m1hi = (unsigned int)__builtin_amdgcn_readlane((int)a1hi, ss);
        unsigned long long msk0 = ((unsigned long long)m0hi << 32) | m0lo;
        unsigned long long msk1 = ((unsigned long long)m1hi << 32) | m1lo;
        int inc0 = (r0 > 0) ? (int)((msk0 >> (r0 - 1)) & 1ULL) : 0;
        int inc1 = (r1 > 0) ? (int)((msk1 >> (r1 - 1)) & 1ULL) : 0;
        r0 -= inc0;
        r1 -= inc1;
    }
    g_map[((size_t)m * 64 + b) * 64 + l] = (unsigned char)r0;
    g_map[((size_t)(NROWS + m) * 64 + b) * 64 + l] = (unsigned char)r1;
}

// ---- scan phase B: compose the 64 block maps per chain (lane = chain).
__global__ __launch_bounds__(256) void scanB_kernel() {
    int c = threadIdx.x;                     // 0..255, single block
    int r = KVAL;
    for (int b = 0; b < 64; ++b) {
        g_entry[(size_t)c * 64 + b] = (unsigned char)r;
        int nxt = g_map[((size_t)c * 64 + b) * 64 + (r - 1)];
        r = (r > 0) ? nxt : 0;
    }
}

// ---- scan phase C: re-walk each block with its known entry r and emit bits.
__global__ __launch_bounds__(256) void scanC_kernel(float* __restrict__ out) {
    int l = threadIdx.x & 63;
    int wid = threadIdx.x >> 6;
    int unit = blockIdx.x * 4 + wid;         // 0..16383
    int c = unit >> 6;
    int b = unit & 63;
    int tens = c >> 7;
    int m = c & (NROWS - 1);
    const unsigned long long* __restrict__ gm = g_mask + (size_t)c * NCOLS + b * 64;
    float* __restrict__ orow = out + (((size_t)tens * 64 + (m >> 1)) * NCOLS) * 2 + (m & 1);

    unsigned long long tile = gm[l];
    unsigned int tlo = (unsigned int)tile;
    unsigned int thi = (unsigned int)(tile >> 32);
    int r = g_entry[(size_t)c * 64 + b];     // uniform
    int myinc = 0;
    #pragma unroll
    for (int ss = 0; ss < 64; ++ss) {
        unsigned int slo = (unsigned int)__builtin_amdgcn_readlane((int)tlo, ss);
        unsigned int shi = (unsigned int)__builtin_amdgcn_readlane((int)thi, ss);
        unsigned long long msk = ((unsigned long long)shi << 32) | slo;
        int inc = (r > 0) ? (int)((msk >> (r - 1)) & 1ULL) : 0;
        myinc = (ss == l) ? inc : myinc;
        r -= inc;
    }
    orow[(size_t)(b * 64 + l) * 2] = (float)myinc;
}

// Marginals via direct normalized sum (round-11/12 form, passing).
__global__ __launch_bounds__(256) void marg_kernel(const float* __restrict__ scores,
                                                   float* __restrict__ out) {
    int l = threadIdx.x & 63;
    int wid = threadIdx.x >> 6;
    int unit = blockIdx.x * 4 + wid;         // 0..8191
    int m  = unit >> 6;
    int t0 = (unit & 63) << 6;
    size_t rowbase = (size_t)m * (NCOLS + 1) * 64;
    const float* __restrict__ P = g_pre + rowbase;
    const float* __restrict__ S = g_suf + rowbase;
    const float* __restrict__ srow = scores + (size_t)(m >> 1) * (NCOLS * 2) + (m & 1);
    float den_full = P[(size_t)NCOLS * 64 + 63];     // log E_k(full row), uniform

    float mres = 0.0f;                       // lane j <- marg of element t0+j
    #pragma unroll 4
    for (int j = 0; j < 64; ++j) {
        int i = t0 + j;
        float vP = (l == 0)  ? 0.0f : P[(size_t)i * 64 + (l - 1)];        // state l
        float vS = (l == 63) ? 0.0f : S[(size_t)(i + 1) * 64 + (62 - l)]; // state 63-l
        float c  = srow[(size_t)i * 2] - den_full;                        // uniform
        float term = __builtin_amdgcn_exp2f((vP + vS + c) * LOG2E);       // <= 1
        float mg = dpp_sum64(term);
        mres = (l == j) ? mg : mres;
    }
    size_t obase = (size_t)2 * 64 * NCOLS * 2;
    out[obase + ((size_t)(m >> 1) * NCOLS + (t0 + l)) * 2 + (m & 1)] = mres;
}

extern "C" void kernel_launch(void* const* d_in, const int* in_sizes, int n_in,
                              void* d_out, int out_size, void* d_ws, size_t ws_size,
                              hipStream_t stream) {
    const float* scores = (const float*)d_in[0];   // (64, 4096, 2) f32
    const float* u      = (const float*)d_in[1];   // (2, 128, 4096) f32
    float* out = (float*)d_out;

    dp_kernel<<<2 * NROWS, 64, 0, stream>>>(scores);
    maskA_kernel<<<2048, 256, 0, stream>>>(scores, u);
    scanB_kernel<<<1, 256, 0, stream>>>();
    scanC_kernel<<<4096, 256, 0, stream>>>(out);
    marg_kernel<<<2048, 256, 0, stream>>>(scores, out);
}

// Round 14
// 258.585 us; speedup vs baseline: 1.8772x; 1.0573x over previous
//
#include <hip/hip_runtime.h>
#include <hip/hip_bf16.h>

#define NROWS 128           // B*E rows
#define NCOLS 4096          // N
#define KVAL  64
#define NEGV  (-1e30f)
#define LOG2E 1.4426950408889634f
#define LN2   0.6931471805599453f

// ESP tables, j=0 column (identically 0) NOT stored: slot j-1 holds state j.
__device__ float g_suf[(size_t)NROWS * (NCOLS + 1) * 64];
__device__ float g_pre[(size_t)NROWS * (NCOLS + 1) * 64];
__device__ unsigned long long g_mask[(size_t)2 * NROWS * NCOLS];   // [chain][t]
__device__ unsigned char g_map  [(size_t)2 * NROWS * 64 * 64];     // [chain][blk][entry-1]
__device__ unsigned char g_entry[(size_t)2 * NROWS * 64];          // [chain][blk]

// wave-wide shift-up-by-1 via DPP wave_shr:1 (0x138); lane 0 -> 0.0f.
__device__ __forceinline__ float shr1z(float x) {
    int r = __builtin_amdgcn_update_dpp(0, __float_as_int(x), 0x138, 0xF, 0xF, true);
    return __int_as_float(r);
}
__device__ __forceinline__ float readlane_f(float v, int lane) {
    return __int_as_float(__builtin_amdgcn_readlane(__float_as_int(v), lane));
}
// fast logaddexp: max(a,b) + ln2 * log2(1 + exp2(-|a-b|*log2e))
// (bit-identical to rounds 3..13 passing table construction)
__device__ __forceinline__ float lae_fast(float a, float b) {
    float mx = fmaxf(a, b);
    float d  = fabsf(a - b);
    float e  = __builtin_amdgcn_exp2f(d * -LOG2E);
    return fmaf(__builtin_amdgcn_logf(1.0f + e), LN2, mx);
}

// DPP wave64 sum reduction (VALU pipe; result broadcast from lane 63).
__device__ __forceinline__ float dpp_sum64(float x) {
#define SSTEP(ctrl, rmask) { int t_ = __builtin_amdgcn_update_dpp(0, \
        __float_as_int(x), ctrl, rmask, 0xF, false); x = x + __int_as_float(t_); }
    SSTEP(0x111, 0xF) SSTEP(0x112, 0xF) SSTEP(0x114, 0xF) SSTEP(0x118, 0xF)
    SSTEP(0x142, 0xA) SSTEP(0x143, 0xC)
#undef SSTEP
    return readlane_f(x, 63);
}

// DP, round-11/13 carry chain (bit-identical); theta tiles loaded directly
// from scores (stride-8B coalesced, off-chain).
__global__ __launch_bounds__(64) void dp_kernel(const float* __restrict__ scores) {
    int blk = blockIdx.x;
    int l = threadIdx.x;
    bool suf = (blk < NROWS);
    int m = suf ? blk : (blk - NROWS);
    float* __restrict__ tab = (suf ? g_suf : g_pre) + (size_t)m * (NCOLS + 1) * 64;
    const float* __restrict__ srow = scores + (size_t)(m >> 1) * (NCOLS * 2) + (m & 1);

    tab[(size_t)(suf ? NCOLS : 0) * 64 + l] = NEGV;    // init state row
    float s = NEGV;
    if (suf) {
        float tile = srow[(size_t)(NCOLS - 64 + l) * 2];       // theta tile
        for (int t0 = NCOLS - 64; t0 >= 0; t0 -= 64) {
            float nxt = (t0 >= 64) ? srow[(size_t)(t0 - 64 + l) * 2] : 0.0f;
            #pragma unroll
            for (int ss = 63; ss >= 0; --ss) {
                float tht = readlane_f(tile, ss);      // broadcast, off-chain
                float b = shr1z(s) + tht;
                s = lae_fast(s, b);
                tab[(size_t)(t0 + ss) * 64 + l] = s;
            }
            tile = nxt;
        }
    } else {
        float tile = srow[(size_t)l * 2];
        for (int t0 = 0; t0 < NCOLS; t0 += 64) {
            float nxt = (t0 + 64 < NCOLS) ? srow[(size_t)(t0 + 64 + l) * 2] : 0.0f;
            #pragma unroll
            for (int ss = 0; ss < 64; ++ss) {
                float tht = readlane_f(tile, ss);
                float b = shr1z(s) + tht;
                s = lae_fast(s, b);
                tab[(size_t)(t0 + ss + 1) * 64 + l] = s;
            }
            tile = nxt;
        }
    }
}

// Fused: sampler masks (round-13 bit path, unchanged) + scanA (in-register)
// + marginals (direct normalized sum; S-side term reuses `num`; P rows
// streamed through a 16-deep prefetch ring, lane-reversed coalesced loads).
__global__ __launch_bounds__(256) void maskA_kernel(const float* __restrict__ scores,
                                                    const float* __restrict__ u,
                                                    float* __restrict__ out) {
    int l = threadIdx.x & 63;
    int wid = threadIdx.x >> 6;
    int unit = blockIdx.x * 4 + wid;         // 0..8191
    int m  = unit >> 6;
    int b  = unit & 63;                      // t-block index
    int t0 = b << 6;
    size_t rowbase = (size_t)m * (NCOLS + 1) * 64;
    const float* __restrict__ S = g_suf + rowbase;
    const float* __restrict__ P = g_pre + rowbase;
    const float* __restrict__ srow = scores + (size_t)(m >> 1) * (NCOLS * 2) + (m & 1);
    const float* __restrict__ u0 = u + (size_t)m * NCOLS;             // ens 0
    const float* __restrict__ u1 = u + (size_t)(NROWS + m) * NCOLS;   // ens 1

    float R[65];                             // S rows t0..t0+64, lane l = slot l
    #pragma unroll
    for (int j = 0; j <= 64; ++j) R[j] = S[(size_t)(t0 + j) * 64 + l];

    float den_full = P[(size_t)NCOLS * 64 + 63];     // log E_k(full row), uniform

    // P-row prefetch ring: lane l reads P[i][62-l] (l=63 reads slot 62, masked).
    int pidx = (l < 63) ? (62 - l) : 62;
    float ring[16];
    #pragma unroll
    for (int j = 0; j < 16; ++j)
        ring[j] = P[(size_t)(t0 + j) * 64 + pidx];

    unsigned long long acc0 = 0, acc1 = 0;   // lane ss <- masks of step t0+ss
    float mres = 0.0f;                       // lane ss <- marg of element t0+ss
    #pragma unroll
    for (int ss = 0; ss < 64; ++ss) {
        int t = t0 + ss;
        // ---- sampler mask (op-for-op identical to passing round-13 kernel)
        float num = shr1z(R[ss + 1]);        // row t+1, state l (lane0 -> 0)
        float den = R[ss];                   // row t, state l+1
        float tht = srow[(size_t)t * 2];     // wave-uniform theta
        float p = __builtin_amdgcn_exp2f(((num + tht) - den) * LOG2E);
        unsigned long long b0 = __ballot(u0[t] < p);
        unsigned long long b1 = __ballot(u1[t] < p);
        acc0 = (l == ss) ? b0 : acc0;
        acc1 = (l == ss) ? b1 : acc1;
        // ---- marginal (output 1): lane l <-> conv index a=63-l, so the
        // S-side term is exactly `num`; P-side from the prefetch ring.
        float vP = (l == 63) ? 0.0f : ring[ss & 15];
        int inext = t + 16;
        if (inext > NCOLS) inext = NCOLS;    // clamp: stay inside P's 4097 rows
        ring[ss & 15] = P[(size_t)inext * 64 + pidx];
        float term = __builtin_amdgcn_exp2f((vP + num + (tht - den_full)) * LOG2E);
        float mg = dpp_sum64(term);
        mres = (l == ss) ? mg : mres;
    }
    g_mask[(size_t)m * NCOLS + t0 + l] = acc0;               // coalesced 512B
    g_mask[(size_t)(NROWS + m) * NCOLS + t0 + l] = acc1;
    size_t obase = (size_t)2 * 64 * NCOLS * 2;
    out[obase + ((size_t)(m >> 1) * NCOLS + (t0 + l)) * 2 + (m & 1)] = mres;

    // ---- fused scanA: walk both ensembles' transition maps from registers.
    unsigned int a0lo = (unsigned int)acc0, a0hi = (unsigned int)(acc0 >> 32);
    unsigned int a1lo = (unsigned int)acc1, a1hi = (unsigned int)(acc1 >> 32);
    int r0 = l + 1, r1 = l + 1;              // entry state for this lane
    #pragma unroll
    for (int ss = 0; ss < 64; ++ss) {
        unsigned int m0lo = (unsigned int)__builtin_amdgcn_readlane((int)a0lo, ss);
        unsigned int m0hi = (unsigned int)__builtin_amdgcn_readlane((int)a0hi, ss);
        unsigned int m1lo = (unsigned int)__builtin_amdgcn_readlane((int)a1lo, ss);
        unsigned int m1hi = (unsigned int)__builtin_amdgcn_readlane((int)a1hi, ss);
        unsigned long long msk0 = ((unsigned long long)m0hi << 32) | m0lo;
        unsigned long long msk1 = ((unsigned long long)m1hi << 32) | m1lo;
        int inc0 = (r0 > 0) ? (int)((msk0 >> (r0 - 1)) & 1ULL) : 0;
        int inc1 = (r1 > 0) ? (int)((msk1 >> (r1 - 1)) & 1ULL) : 0;
        r0 -= inc0;
        r1 -= inc1;
    }
    g_map[((size_t)m * 64 + b) * 64 + l] = (unsigned char)r0;
    g_map[((size_t)(NROWS + m) * 64 + b) * 64 + l] = (unsigned char)r1;
}

// ---- scan phase B: compose the 64 block maps per chain (lane = chain).
__global__ __launch_bounds__(256) void scanB_kernel() {
    int c = threadIdx.x;                     // 0..255, single block
    int r = KVAL;
    for (int b = 0; b < 64; ++b) {
        g_entry[(size_t)c * 64 + b] = (unsigned char)r;
        int nxt = g_map[((size_t)c * 64 + b) * 64 + (r - 1)];
        r = (r > 0) ? nxt : 0;
    }
}

// ---- scan phase C: re-walk each block with its known entry r and emit bits.
__global__ __launch_bounds__(256) void scanC_kernel(float* __restrict__ out) {
    int l = threadIdx.x & 63;
    int wid = threadIdx.x >> 6;
    int unit = blockIdx.x * 4 + wid;         // 0..16383
    int c = unit >> 6;
    int b = unit & 63;
    int tens = c >> 7;
    int m = c & (NROWS - 1);
    const unsigned long long* __restrict__ gm = g_mask + (size_t)c * NCOLS + b * 64;
    float* __restrict__ orow = out + (((size_t)tens * 64 + (m >> 1)) * NCOLS) * 2 + (m & 1);

    unsigned long long tile = gm[l];
    unsigned int tlo = (unsigned int)tile;
    unsigned int thi = (unsigned int)(tile >> 32);
    int r = g_entry[(size_t)c * 64 + b];     // uniform
    int myinc = 0;
    #pragma unroll
    for (int ss = 0; ss < 64; ++ss) {
        unsigned int slo = (unsigned int)__builtin_amdgcn_readlane((int)tlo, ss);
        unsigned int shi = (unsigned int)__builtin_amdgcn_readlane((int)thi, ss);
        unsigned long long msk = ((unsigned long long)shi << 32) | slo;
        int inc = (r > 0) ? (int)((msk >> (r - 1)) & 1ULL) : 0;
        myinc = (ss == l) ? inc : myinc;
        r -= inc;
    }
    orow[(size_t)(b * 64 + l) * 2] = (float)myinc;
}

extern "C" void kernel_launch(void* const* d_in, const int* in_sizes, int n_in,
                              void* d_out, int out_size, void* d_ws, size_t ws_size,
                              hipStream_t stream) {
    const float* scores = (const float*)d_in[0];   // (64, 4096, 2) f32
    const float* u      = (const float*)d_in[1];   // (2, 128, 4096) f32
    float* out = (float*)d_out;

    dp_kernel<<<2 * NROWS, 64, 0, stream>>>(scores);
    maskA_kernel<<<2048, 256, 0, stream>>>(scores, u, out);
    scanB_kernel<<<1, 256, 0, stream>>>();
    scanC_kernel<<<4096, 256, 0, stream>>>(out);
}

// Round 15
// 250.967 us; speedup vs baseline: 1.9342x; 1.0304x over previous
//
#include <hip/hip_runtime.h>
#include <hip/hip_bf16.h>

#define NROWS 128           // B*E rows
#define NCOLS 4096          // N
#define KVAL  64
#define NEGV  (-1e30f)
#define LOG2E 1.4426950408889634f
#define LN2   0.6931471805599453f

// ESP tables, j=0 column (identically 0) NOT stored: slot j-1 holds state j.
__device__ float g_suf[(size_t)NROWS * (NCOLS + 1) * 64];
__device__ float g_pre[(size_t)NROWS * (NCOLS + 1) * 64];
__device__ unsigned long long g_mask[(size_t)2 * NROWS * NCOLS];   // [chain][t]
__device__ unsigned char g_map  [(size_t)2 * NROWS * 64 * 64];     // [chain][blk][entry-1]
__device__ unsigned char g_entry[(size_t)2 * NROWS * 64];          // [chain][blk]

// wave-wide shift-up-by-1 via DPP wave_shr:1 (0x138); lane 0 -> 0.0f.
__device__ __forceinline__ float shr1z(float x) {
    int r = __builtin_amdgcn_update_dpp(0, __float_as_int(x), 0x138, 0xF, 0xF, true);
    return __int_as_float(r);
}
__device__ __forceinline__ float readlane_f(float v, int lane) {
    return __int_as_float(__builtin_amdgcn_readlane(__float_as_int(v), lane));
}
// fast logaddexp: max(a,b) + ln2 * log2(1 + exp2(-|a-b|*log2e))
// (bit-identical to rounds 3..14 passing table construction)
__device__ __forceinline__ float lae_fast(float a, float b) {
    float mx = fmaxf(a, b);
    float d  = fabsf(a - b);
    float e  = __builtin_amdgcn_exp2f(d * -LOG2E);
    return fmaf(__builtin_amdgcn_logf(1.0f + e), LN2, mx);
}

// DPP wave64 sum reduction (VALU pipe; result broadcast from lane 63).
__device__ __forceinline__ float dpp_sum64(float x) {
#define SSTEP(ctrl, rmask) { int t_ = __builtin_amdgcn_update_dpp(0, \
        __float_as_int(x), ctrl, rmask, 0xF, false); x = x + __int_as_float(t_); }
    SSTEP(0x111, 0xF) SSTEP(0x112, 0xF) SSTEP(0x114, 0xF) SSTEP(0x118, 0xF)
    SSTEP(0x142, 0xA) SSTEP(0x143, 0xC)
#undef SSTEP
    return readlane_f(x, 63);
}

// DP, round-11/14 carry chain (bit-identical). __launch_bounds__(64, 1):
// this kernel runs 1 wave/CU -- let the allocator use the full VGPR budget
// so the scheduler can hoist prefetches/stores into the chain's stall gaps.
__global__ __launch_bounds__(64, 1) void dp_kernel(const float* __restrict__ scores) {
    int blk = blockIdx.x;
    int l = threadIdx.x;
    bool suf = (blk < NROWS);
    int m = suf ? blk : (blk - NROWS);
    float* __restrict__ tab = (suf ? g_suf : g_pre) + (size_t)m * (NCOLS + 1) * 64;
    const float* __restrict__ srow = scores + (size_t)(m >> 1) * (NCOLS * 2) + (m & 1);

    tab[(size_t)(suf ? NCOLS : 0) * 64 + l] = NEGV;    // init state row
    float s = NEGV;
    if (suf) {
        float tile = srow[(size_t)(NCOLS - 64 + l) * 2];       // theta tile
        for (int t0 = NCOLS - 64; t0 >= 0; t0 -= 64) {
            float nxt = (t0 >= 64) ? srow[(size_t)(t0 - 64 + l) * 2] : 0.0f;
            #pragma unroll
            for (int ss = 63; ss >= 0; --ss) {
                float tht = readlane_f(tile, ss);      // broadcast, off-chain
                float b = shr1z(s) + tht;
                s = lae_fast(s, b);
                tab[(size_t)(t0 + ss) * 64 + l] = s;
            }
            tile = nxt;
        }
    } else {
        float tile = srow[(size_t)l * 2];
        for (int t0 = 0; t0 < NCOLS; t0 += 64) {
            float nxt = (t0 + 64 < NCOLS) ? srow[(size_t)(t0 + 64 + l) * 2] : 0.0f;
            #pragma unroll
            for (int ss = 0; ss < 64; ++ss) {
                float tht = readlane_f(tile, ss);
                float b = shr1z(s) + tht;
                s = lae_fast(s, b);
                tab[(size_t)(t0 + ss + 1) * 64 + l] = s;
            }
            tile = nxt;
        }
    }
}

// Fused: sampler masks + scanA + marginals (round-14 expressions, bit-identical).
// NEW: u0/u1/theta delivered via coalesced register tiles + v_readlane instead
// of 192 wave-uniform global loads inside the unrolled loop (same float values
// -> same ballot bits; removes the per-step lgkmcnt stalls).
__global__ __launch_bounds__(256) void maskA_kernel(const float* __restrict__ scores,
                                                    const float* __restrict__ u,
                                                    float* __restrict__ out) {
    int l = threadIdx.x & 63;
    int wid = threadIdx.x >> 6;
    int unit = blockIdx.x * 4 + wid;         // 0..8191
    int m  = unit >> 6;
    int b  = unit & 63;                      // t-block index
    int t0 = b << 6;
    size_t rowbase = (size_t)m * (NCOLS + 1) * 64;
    const float* __restrict__ S = g_suf + rowbase;
    const float* __restrict__ P = g_pre + rowbase;
    const float* __restrict__ srow = scores + (size_t)(m >> 1) * (NCOLS * 2) + (m & 1);
    const float* __restrict__ u0 = u + (size_t)m * NCOLS;             // ens 0
    const float* __restrict__ u1 = u + (size_t)(NROWS + m) * NCOLS;   // ens 1

    // register tiles: lane l holds step t0+l's theta/u values
    float thtile = srow[(size_t)(t0 + l) * 2];
    float u0tile = u0[t0 + l];
    float u1tile = u1[t0 + l];

    float R[65];                             // S rows t0..t0+64, lane l = slot l
    #pragma unroll
    for (int j = 0; j <= 64; ++j) R[j] = S[(size_t)(t0 + j) * 64 + l];

    float den_full = P[(size_t)NCOLS * 64 + 63];     // log E_k(full row), uniform

    // P-row prefetch ring: lane l reads P[i][62-l] (l=63 reads slot 62, masked).
    int pidx = (l < 63) ? (62 - l) : 62;
    float ring[16];
    #pragma unroll
    for (int j = 0; j < 16; ++j)
        ring[j] = P[(size_t)(t0 + j) * 64 + pidx];

    unsigned long long acc0 = 0, acc1 = 0;   // lane ss <- masks of step t0+ss
    float mres = 0.0f;                       // lane ss <- marg of element t0+ss
    #pragma unroll
    for (int ss = 0; ss < 64; ++ss) {
        int t = t0 + ss;
        // ---- sampler mask (expression identical to passing round-14 kernel)
        float num = shr1z(R[ss + 1]);        // row t+1, state l (lane0 -> 0)
        float den = R[ss];                   // row t, state l+1
        float tht = readlane_f(thtile, ss);  // broadcast (same value as before)
        float uu0 = readlane_f(u0tile, ss);
        float uu1 = readlane_f(u1tile, ss);
        float p = __builtin_amdgcn_exp2f(((num + tht) - den) * LOG2E);
        unsigned long long b0 = __ballot(uu0 < p);
        unsigned long long b1 = __ballot(uu1 < p);
        acc0 = (l == ss) ? b0 : acc0;
        acc1 = (l == ss) ? b1 : acc1;
        // ---- marginal (output 1): lane l <-> conv index a=63-l, so the
        // S-side term is exactly `num`; P-side from the prefetch ring.
        float vP = (l == 63) ? 0.0f : ring[ss & 15];
        int inext = t + 16;
        if (inext > NCOLS) inext = NCOLS;    // clamp: stay inside P's 4097 rows
        ring[ss & 15] = P[(size_t)inext * 64 + pidx];
        float term = __builtin_amdgcn_exp2f((vP + num + (tht - den_full)) * LOG2E);
        float mg = dpp_sum64(term);
        mres = (l == ss) ? mg : mres;
    }
    g_mask[(size_t)m * NCOLS + t0 + l] = acc0;               // coalesced 512B
    g_mask[(size_t)(NROWS + m) * NCOLS + t0 + l] = acc1;
    size_t obase = (size_t)2 * 64 * NCOLS * 2;
    out[obase + ((size_t)(m >> 1) * NCOLS + (t0 + l)) * 2 + (m & 1)] = mres;

    // ---- fused scanA: walk both ensembles' transition maps from registers.
    unsigned int a0lo = (unsigned int)acc0, a0hi = (unsigned int)(acc0 >> 32);
    unsigned int a1lo = (unsigned int)acc1, a1hi = (unsigned int)(acc1 >> 32);
    int r0 = l + 1, r1 = l + 1;              // entry state for this lane
    #pragma unroll
    for (int ss = 0; ss < 64; ++ss) {
        unsigned int m0lo = (unsigned int)__builtin_amdgcn_readlane((int)a0lo, ss);
        unsigned int m0hi = (unsigned int)__builtin_amdgcn_readlane((int)a0hi, ss);
        unsigned int m1lo = (unsigned int)__builtin_amdgcn_readlane((int)a1lo, ss);
        unsigned int m1hi = (unsigned int)__builtin_amdgcn_readlane((int)a1hi, ss);
        unsigned long long msk0 = ((unsigned long long)m0hi << 32) | m0lo;
        unsigned long long msk1 = ((unsigned long long)m1hi << 32) | m1lo;
        int inc0 = (r0 > 0) ? (int)((msk0 >> (r0 - 1)) & 1ULL) : 0;
        int inc1 = (r1 > 0) ? (int)((msk1 >> (r1 - 1)) & 1ULL) : 0;
        r0 -= inc0;
        r1 -= inc1;
    }
    g_map[((size_t)m * 64 + b) * 64 + l] = (unsigned char)r0;
    g_map[((size_t)(NROWS + m) * 64 + b) * 64 + l] = (unsigned char)r1;
}

// ---- scan phase B: compose the 64 block maps per chain (lane = chain).
__global__ __launch_bounds__(256) void scanB_kernel() {
    int c = threadIdx.x;                     // 0..255, single block
    int r = KVAL;
    for (int b = 0; b < 64; ++b) {
        g_entry[(size_t)c * 64 + b] = (unsigned char)r;
        int nxt = g_map[((size_t)c * 64 + b) * 64 + (r - 1)];
        r = (r > 0) ? nxt : 0;
    }
}

// ---- scan phase C: re-walk each block with its known entry r and emit bits.
__global__ __launch_bounds__(256) void scanC_kernel(float* __restrict__ out) {
    int l = threadIdx.x & 63;
    int wid = threadIdx.x >> 6;
    int unit = blockIdx.x * 4 + wid;         // 0..16383
    int c = unit >> 6;
    int b = unit & 63;
    int tens = c >> 7;
    int m = c & (NROWS - 1);
    const unsigned long long* __restrict__ gm = g_mask + (size_t)c * NCOLS + b * 64;
    float* __restrict__ orow = out + (((size_t)tens * 64 + (m >> 1)) * NCOLS) * 2 + (m & 1);

    unsigned long long tile = gm[l];
    unsigned int tlo = (unsigned int)tile;
    unsigned int thi = (unsigned int)(tile >> 32);
    int r = g_entry[(size_t)c * 64 + b];     // uniform
    int myinc = 0;
    #pragma unroll
    for (int ss = 0; ss < 64; ++ss) {
        unsigned int slo = (unsigned int)__builtin_amdgcn_readlane((int)tlo, ss);
        unsigned int shi = (unsigned int)__builtin_amdgcn_readlane((int)thi, ss);
        unsigned long long msk = ((unsigned long long)shi << 32) | slo;
        int inc = (r > 0) ? (int)((msk >> (r - 1)) & 1ULL) : 0;
        myinc = (ss == l) ? inc : myinc;
        r -= inc;
    }
    orow[(size_t)(b * 64 + l) * 2] = (float)myinc;
}

extern "C" void kernel_launch(void* const* d_in, const int* in_sizes, int n_in,
                              void* d_out, int out_size, void* d_ws, size_t ws_size,
                              hipStream_t stream) {
    const float* scores = (const float*)d_in[0];   // (64, 4096, 2) f32
    const float* u      = (const float*)d_in[1];   // (2, 128, 4096) f32
    float* out = (float*)d_out;

    dp_kernel<<<2 * NROWS, 64, 0, stream>>>(scores);
    maskA_kernel<<<2048, 256, 0, stream>>>(scores, u, out);
    scanB_kernel<<<1, 256, 0, stream>>>();
    scanC_kernel<<<4096, 256, 0, stream>>>(out);
}

// Round 16
// 246.424 us; speedup vs baseline: 1.9698x; 1.0184x over previous
//
#include <hip/hip_runtime.h>
#include <hip/hip_bf16.h>

#define NROWS 128           // B*E rows
#define NCOLS 4096          // N
#define KVAL  64
#define NEGV  (-1e30f)
#define LOG2E 1.4426950408889634f
#define LN2   0.6931471805599453f

// ESP tables, j=0 column (identically 0) NOT stored: slot j-1 holds state j.
__device__ float g_suf[(size_t)NROWS * (NCOLS + 1) * 64];
__device__ float g_pre[(size_t)NROWS * (NCOLS + 1) * 64];
__device__ unsigned long long g_mask[(size_t)2 * NROWS * NCOLS];   // [chain][t]
__device__ unsigned char g_map  [(size_t)2 * NROWS * 64 * 64];     // [chain][blk][entry-1]
__device__ unsigned char g_entry[(size_t)2 * NROWS * 64];          // [chain][blk]
__device__ unsigned long long g_incs[(size_t)2 * NROWS * 64 * 64]; // [chain][blk][entry-1]

// wave-wide shift-up-by-1 via DPP wave_shr:1 (0x138); lane 0 -> 0.0f.
__device__ __forceinline__ float shr1z(float x) {
    int r = __builtin_amdgcn_update_dpp(0, __float_as_int(x), 0x138, 0xF, 0xF, true);
    return __int_as_float(r);
}
__device__ __forceinline__ float readlane_f(float v, int lane) {
    return __int_as_float(__builtin_amdgcn_readlane(__float_as_int(v), lane));
}
// fast logaddexp: max(a,b) + ln2 * log2(1 + exp2(-|a-b|*log2e))
// (bit-identical to rounds 3..15 passing table construction)
__device__ __forceinline__ float lae_fast(float a, float b) {
    float mx = fmaxf(a, b);
    float d  = fabsf(a - b);
    float e  = __builtin_amdgcn_exp2f(d * -LOG2E);
    return fmaf(__builtin_amdgcn_logf(1.0f + e), LN2, mx);
}

// DPP wave64 sum reduction (VALU pipe; result broadcast from lane 63).
__device__ __forceinline__ float dpp_sum64(float x) {
#define SSTEP(ctrl, rmask) { int t_ = __builtin_amdgcn_update_dpp(0, \
        __float_as_int(x), ctrl, rmask, 0xF, false); x = x + __int_as_float(t_); }
    SSTEP(0x111, 0xF) SSTEP(0x112, 0xF) SSTEP(0x114, 0xF) SSTEP(0x118, 0xF)
    SSTEP(0x142, 0xA) SSTEP(0x143, 0xC)
#undef SSTEP
    return readlane_f(x, 63);
}

// DP, round-11/15 carry chain (bit-identical); theta tiles loaded directly
// from scores (stride-8B coalesced, off-chain). Structural floor: 4096
// sequential steps x ~88cy (2 TRANS + 6 VALU dependent + DPP) ~= 150us.
__global__ __launch_bounds__(64, 1) void dp_kernel(const float* __restrict__ scores) {
    int blk = blockIdx.x;
    int l = threadIdx.x;
    bool suf = (blk < NROWS);
    int m = suf ? blk : (blk - NROWS);
    float* __restrict__ tab = (suf ? g_suf : g_pre) + (size_t)m * (NCOLS + 1) * 64;
    const float* __restrict__ srow = scores + (size_t)(m >> 1) * (NCOLS * 2) + (m & 1);

    tab[(size_t)(suf ? NCOLS : 0) * 64 + l] = NEGV;    // init state row
    float s = NEGV;
    if (suf) {
        float tile = srow[(size_t)(NCOLS - 64 + l) * 2];       // theta tile
        for (int t0 = NCOLS - 64; t0 >= 0; t0 -= 64) {
            float nxt = (t0 >= 64) ? srow[(size_t)(t0 - 64 + l) * 2] : 0.0f;
            #pragma unroll
            for (int ss = 63; ss >= 0; --ss) {
                float tht = readlane_f(tile, ss);      // broadcast, off-chain
                float b = shr1z(s) + tht;
                s = lae_fast(s, b);
                tab[(size_t)(t0 + ss) * 64 + l] = s;
            }
            tile = nxt;
        }
    } else {
        float tile = srow[(size_t)l * 2];
        for (int t0 = 0; t0 < NCOLS; t0 += 64) {
            float nxt = (t0 + 64 < NCOLS) ? srow[(size_t)(t0 + 64 + l) * 2] : 0.0f;
            #pragma unroll
            for (int ss = 0; ss < 64; ++ss) {
                float tht = readlane_f(tile, ss);
                float b = shr1z(s) + tht;
                s = lae_fast(s, b);
                tab[(size_t)(t0 + ss + 1) * 64 + l] = s;
            }
            tile = nxt;
        }
    }
}

// Fused: sampler masks + scanA (+inc vectors) + marginals.
// Round-15 expressions bit-for-bit; S rows now stream through a 16-deep
// register ring (like P) instead of R[65], cutting ~50 VGPRs so occupancy
// rises from ~3 to ~8 waves/SIMD (hides the remaining memory latency).
__global__ __launch_bounds__(256) void maskA_kernel(const float* __restrict__ scores,
                                                    const float* __restrict__ u,
                                                    float* __restrict__ out) {
    int l = threadIdx.x & 63;
    int wid = threadIdx.x >> 6;
    int unit = blockIdx.x * 4 + wid;         // 0..8191
    int m  = unit >> 6;
    int b  = unit & 63;                      // t-block index
    int t0 = b << 6;
    size_t rowbase = (size_t)m * (NCOLS + 1) * 64;
    const float* __restrict__ S = g_suf + rowbase;
    const float* __restrict__ P = g_pre + rowbase;
    const float* __restrict__ srow = scores + (size_t)(m >> 1) * (NCOLS * 2) + (m & 1);
    const float* __restrict__ u0 = u + (size_t)m * NCOLS;             // ens 0
    const float* __restrict__ u1 = u + (size_t)(NROWS + m) * NCOLS;   // ens 1

    // register tiles: lane l holds step t0+l's theta/u values
    float thtile = srow[(size_t)(t0 + l) * 2];
    float u0tile = u0[t0 + l];
    float u1tile = u1[t0 + l];

    float den_full = P[(size_t)NCOLS * 64 + 63];     // log E_k(full row), uniform

    // P-row prefetch ring: lane l reads P[i][62-l] (l=63 reads slot 62, masked).
    int pidx = (l < 63) ? (62 - l) : 62;
    float pring[16];
    #pragma unroll
    for (int j = 0; j < 16; ++j)
        pring[j] = P[(size_t)(t0 + j) * 64 + pidx];

    // S-row ring: den carried in Dcur; ring holds rows t0+1 .. t0+16.
    float Dcur = S[(size_t)t0 * 64 + l];
    float sring[16];
    #pragma unroll
    for (int j = 0; j < 16; ++j)
        sring[j] = S[(size_t)(t0 + 1 + j) * 64 + l];

    unsigned long long acc0 = 0, acc1 = 0;   // lane ss <- masks of step t0+ss
    float mres = 0.0f;                       // lane ss <- marg of element t0+ss
    #pragma unroll
    for (int ss = 0; ss < 64; ++ss) {
        int t = t0 + ss;
        float Dnext = sring[ss & 15];        // S row t+1 (same value as old R[ss+1])
        int snext = t0 + ss + 17;
        if (snext > NCOLS) snext = NCOLS;    // clamp (prefetch values unused)
        sring[ss & 15] = S[(size_t)snext * 64 + l];
        // ---- sampler mask (expression identical to passing round-15 kernel)
        float num = shr1z(Dnext);            // row t+1, state l (lane0 -> 0)
        float den = Dcur;                    // row t, state l+1
        float tht = readlane_f(thtile, ss);
        float uu0 = readlane_f(u0tile, ss);
        float uu1 = readlane_f(u1tile, ss);
        float p = __builtin_amdgcn_exp2f(((num + tht) - den) * LOG2E);
        unsigned long long b0 = __ballot(uu0 < p);
        unsigned long long b1 = __ballot(uu1 < p);
        acc0 = (l == ss) ? b0 : acc0;
        acc1 = (l == ss) ? b1 : acc1;
        // ---- marginal (output 1): S-side term is exactly `num`; P from ring.
        float vP = (l == 63) ? 0.0f : pring[ss & 15];
        int inext = t + 16;
        if (inext > NCOLS) inext = NCOLS;
        pring[ss & 15] = P[(size_t)inext * 64 + pidx];
        float term = __builtin_amdgcn_exp2f((vP + num + (tht - den_full)) * LOG2E);
        float mg = dpp_sum64(term);
        mres = (l == ss) ? mg : mres;
        Dcur = Dnext;
    }
    g_mask[(size_t)m * NCOLS + t0 + l] = acc0;               // coalesced 512B
    g_mask[(size_t)(NROWS + m) * NCOLS + t0 + l] = acc1;
    size_t obase = (size_t)2 * 64 * NCOLS * 2;
    out[obase + ((size_t)(m >> 1) * NCOLS + (t0 + l)) * 2 + (m & 1)] = mres;

    // ---- fused scanA: walk both ensembles' maps; ALSO record each entry's
    // full inc-vector so scanC needs no re-walk.
    unsigned int a0lo = (unsigned int)acc0, a0hi = (unsigned int)(acc0 >> 32);
    unsigned int a1lo = (unsigned int)acc1, a1hi = (unsigned int)(acc1 >> 32);
    int r0 = l + 1, r1 = l + 1;              // entry state for this lane
    unsigned long long bits0 = 0, bits1 = 0;
    #pragma unroll
    for (int ss = 0; ss < 64; ++ss) {
        unsigned int m0lo = (unsigned int)__builtin_amdgcn_readlane((int)a0lo, ss);
        unsigned int m0hi = (unsigned int)__builtin_amdgcn_readlane((int)a0hi, ss);
        unsigned int m1lo = (unsigned int)__builtin_amdgcn_readlane((int)a1lo, ss);
        unsigned int m1hi = (unsigned int)__builtin_amdgcn_readlane((int)a1hi, ss);
        unsigned long long msk0 = ((unsigned long long)m0hi << 32) | m0lo;
        unsigned long long msk1 = ((unsigned long long)m1hi << 32) | m1lo;
        int inc0 = (r0 > 0) ? (int)((msk0 >> (r0 - 1)) & 1ULL) : 0;
        int inc1 = (r1 > 0) ? (int)((msk1 >> (r1 - 1)) & 1ULL) : 0;
        bits0 |= ((unsigned long long)inc0) << ss;
        bits1 |= ((unsigned long long)inc1) << ss;
        r0 -= inc0;
        r1 -= inc1;
    }
    g_map[((size_t)m * 64 + b) * 64 + l] = (unsigned char)r0;
    g_map[((size_t)(NROWS + m) * 64 + b) * 64 + l] = (unsigned char)r1;
    g_incs[((size_t)m * 64 + b) * 64 + l] = bits0;
    g_incs[((size_t)(NROWS + m) * 64 + b) * 64 + l] = bits1;
}

// ---- scan phase B: compose the 64 block maps per chain (lane = chain).
__global__ __launch_bounds__(256) void scanB_kernel() {
    int c = threadIdx.x;                     // 0..255, single block
    int r = KVAL;
    for (int b = 0; b < 64; ++b) {
        g_entry[(size_t)c * 64 + b] = (unsigned char)r;
        int nxt = g_map[((size_t)c * 64 + b) * 64 + (r - 1)];
        r = (r > 0) ? nxt : 0;
    }
}

// ---- scan phase C: read the precomputed inc-vector for the known entry
// state and expand to floats (no re-walk; integer-exact by construction).
__global__ __launch_bounds__(256) void scanC_kernel(float* __restrict__ out) {
    int l = threadIdx.x & 63;
    int wid = threadIdx.x >> 6;
    int unit = blockIdx.x * 4 + wid;         // 0..16383
    int c = unit >> 6;
    int b = unit & 63;
    int tens = c >> 7;
    int m = c & (NROWS - 1);
    float* __restrict__ orow = out + (((size_t)tens * 64 + (m >> 1)) * NCOLS) * 2 + (m & 1);

    int r = g_entry[(size_t)c * 64 + b];     // uniform
    unsigned long long incvec = (r > 0)
        ? g_incs[((size_t)c * 64 + b) * 64 + (r - 1)] : 0ULL;   // uniform
    orow[(size_t)(b * 64 + l) * 2] = (float)((incvec >> l) & 1ULL);
}

extern "C" void kernel_launch(void* const* d_in, const int* in_sizes, int n_in,
                              void* d_out, int out_size, void* d_ws, size_t ws_size,
                              hipStream_t stream) {
    const float* scores = (const float*)d_in[0];   // (64, 4096, 2) f32
    const float* u      = (const float*)d_in[1];   // (2, 128, 4096) f32
    float* out = (float*)d_out;

    dp_kernel<<<2 * NROWS, 64, 0, stream>>>(scores);
    maskA_kernel<<<2048, 256, 0, stream>>>(scores, u, out);
    scanB_kernel<<<1, 256, 0, stream>>>();
    scanC_kernel<<<4096, 256, 0, stream>>>(out);
}

// Round 17
// 241.002 us; speedup vs baseline: 2.0141x; 1.0225x over previous
//
#include <hip/hip_runtime.h>
#include <hip/hip_bf16.h>

#define NROWS 128           // B*E rows
#define NCOLS 4096          // N
#define KVAL  64
#define NEGV  (-1e30f)
#define LOG2E 1.4426950408889634f
#define LN2   0.6931471805599453f

// ESP tables, j=0 column (identically 0) NOT stored: slot j-1 holds state j.
__device__ float g_suf[(size_t)NROWS * (NCOLS + 1) * 64];
__device__ float g_pre[(size_t)NROWS * (NCOLS + 1) * 64];
__device__ unsigned long long g_mask[(size_t)2 * NROWS * NCOLS];   // [chain][t]
__device__ unsigned char g_map  [(size_t)2 * NROWS * 64 * 64];     // [chain][blk][entry-1]
__device__ unsigned char g_entry[(size_t)2 * NROWS * 64];          // [chain][blk]
__device__ unsigned long long g_incs[(size_t)2 * NROWS * 64 * 64]; // [chain][blk][entry-1]

// wave-wide shift-up-by-1 via DPP wave_shr:1 (0x138); lane 0 -> 0.0f.
__device__ __forceinline__ float shr1z(float x) {
    int r = __builtin_amdgcn_update_dpp(0, __float_as_int(x), 0x138, 0xF, 0xF, true);
    return __int_as_float(r);
}
__device__ __forceinline__ float readlane_f(float v, int lane) {
    return __int_as_float(__builtin_amdgcn_readlane(__float_as_int(v), lane));
}
// fast logaddexp: max(a,b) + ln2 * log2(1 + exp2(-|a-b|*log2e))
// (bit-identical to rounds 3..16 passing table construction)
__device__ __forceinline__ float lae_fast(float a, float b) {
    float mx = fmaxf(a, b);
    float d  = fabsf(a - b);
    float e  = __builtin_amdgcn_exp2f(d * -LOG2E);
    return fmaf(__builtin_amdgcn_logf(1.0f + e), LN2, mx);
}

// DPP wave64 sum reduction (VALU pipe; result broadcast from lane 63).
__device__ __forceinline__ float dpp_sum64(float x) {
#define SSTEP(ctrl, rmask) { int t_ = __builtin_amdgcn_update_dpp(0, \
        __float_as_int(x), ctrl, rmask, 0xF, false); x = x + __int_as_float(t_); }
    SSTEP(0x111, 0xF) SSTEP(0x112, 0xF) SSTEP(0x114, 0xF) SSTEP(0x118, 0xF)
    SSTEP(0x142, 0xA) SSTEP(0x143, 0xC)
#undef SSTEP
    return readlane_f(x, 63);
}

// DP, round-11/16 carry chain (bit-identical); theta tiles loaded directly
// from scores (stride-8B coalesced, off-chain). Structural floor: 4096
// sequential steps x ~88cy (2 TRANS + 6 VALU dependent + DPP) ~= 150us.
__global__ __launch_bounds__(64, 1) void dp_kernel(const float* __restrict__ scores) {
    int blk = blockIdx.x;
    int l = threadIdx.x;
    bool suf = (blk < NROWS);
    int m = suf ? blk : (blk - NROWS);
    float* __restrict__ tab = (suf ? g_suf : g_pre) + (size_t)m * (NCOLS + 1) * 64;
    const float* __restrict__ srow = scores + (size_t)(m >> 1) * (NCOLS * 2) + (m & 1);

    tab[(size_t)(suf ? NCOLS : 0) * 64 + l] = NEGV;    // init state row
    float s = NEGV;
    if (suf) {
        float tile = srow[(size_t)(NCOLS - 64 + l) * 2];       // theta tile
        for (int t0 = NCOLS - 64; t0 >= 0; t0 -= 64) {
            float nxt = (t0 >= 64) ? srow[(size_t)(t0 - 64 + l) * 2] : 0.0f;
            #pragma unroll
            for (int ss = 63; ss >= 0; --ss) {
                float tht = readlane_f(tile, ss);      // broadcast, off-chain
                float b = shr1z(s) + tht;
                s = lae_fast(s, b);
                tab[(size_t)(t0 + ss) * 64 + l] = s;
            }
            tile = nxt;
        }
    } else {
        float tile = srow[(size_t)l * 2];
        for (int t0 = 0; t0 < NCOLS; t0 += 64) {
            float nxt = (t0 + 64 < NCOLS) ? srow[(size_t)(t0 + 64 + l) * 2] : 0.0f;
            #pragma unroll
            for (int ss = 0; ss < 64; ++ss) {
                float tht = readlane_f(tile, ss);
                float b = shr1z(s) + tht;
                s = lae_fast(s, b);
                tab[(size_t)(t0 + ss + 1) * 64 + l] = s;
            }
            tile = nxt;
        }
    }
}

// Fused: sampler masks + scanA (+inc vectors) + marginals.
// Round-16 values bit-for-bit. NEW: dead ring prefetches (entries written at
// step ss>=48, never consumed) are clamped to BLOCK-LOCAL rows (t0+64/t0+63)
// instead of NCOLS, so they hit L2-resident lines -- kills the +25% HBM
// over-fetch on both the S and P streams (~66 MB).
__global__ __launch_bounds__(256) void maskA_kernel(const float* __restrict__ scores,
                                                    const float* __restrict__ u,
                                                    float* __restrict__ out) {
    int l = threadIdx.x & 63;
    int wid = threadIdx.x >> 6;
    int unit = blockIdx.x * 4 + wid;         // 0..8191
    int m  = unit >> 6;
    int b  = unit & 63;                      // t-block index
    int t0 = b << 6;
    size_t rowbase = (size_t)m * (NCOLS + 1) * 64;
    const float* __restrict__ S = g_suf + rowbase;
    const float* __restrict__ P = g_pre + rowbase;
    const float* __restrict__ srow = scores + (size_t)(m >> 1) * (NCOLS * 2) + (m & 1);
    const float* __restrict__ u0 = u + (size_t)m * NCOLS;             // ens 0
    const float* __restrict__ u1 = u + (size_t)(NROWS + m) * NCOLS;   // ens 1

    // register tiles: lane l holds step t0+l's theta/u values
    float thtile = srow[(size_t)(t0 + l) * 2];
    float u0tile = u0[t0 + l];
    float u1tile = u1[t0 + l];

    float den_full = P[(size_t)NCOLS * 64 + 63];     // log E_k(full row), uniform

    // P-row prefetch ring: lane l reads P[i][62-l] (l=63 reads slot 62, masked).
    int pidx = (l < 63) ? (62 - l) : 62;
    float pring[16];
    #pragma unroll
    for (int j = 0; j < 16; ++j)
        pring[j] = P[(size_t)(t0 + j) * 64 + pidx];

    // S-row ring: den carried in Dcur; ring holds rows t0+1 .. t0+16.
    float Dcur = S[(size_t)t0 * 64 + l];
    float sring[16];
    #pragma unroll
    for (int j = 0; j < 16; ++j)
        sring[j] = S[(size_t)(t0 + 1 + j) * 64 + l];

    unsigned long long acc0 = 0, acc1 = 0;   // lane ss <- masks of step t0+ss
    float mres = 0.0f;                       // lane ss <- marg of element t0+ss
    #pragma unroll
    for (int ss = 0; ss < 64; ++ss) {
        int t = t0 + ss;
        float Dnext = sring[ss & 15];        // S row t+1
        int snext = t0 + ss + 17;
        if (snext > t0 + 64) snext = t0 + 64;   // dead prefetch -> block-local (L2 hit)
        sring[ss & 15] = S[(size_t)snext * 64 + l];
        // ---- sampler mask (expression identical to passing round-16 kernel)
        float num = shr1z(Dnext);            // row t+1, state l (lane0 -> 0)
        float den = Dcur;                    // row t, state l+1
        float tht = readlane_f(thtile, ss);
        float uu0 = readlane_f(u0tile, ss);
        float uu1 = readlane_f(u1tile, ss);
        float p = __builtin_amdgcn_exp2f(((num + tht) - den) * LOG2E);
        unsigned long long b0 = __ballot(uu0 < p);
        unsigned long long b1 = __ballot(uu1 < p);
        acc0 = (l == ss) ? b0 : acc0;
        acc1 = (l == ss) ? b1 : acc1;
        // ---- marginal (output 1): S-side term is exactly `num`; P from ring.
        float vP = (l == 63) ? 0.0f : pring[ss & 15];
        int inext = t + 16;
        if (inext > t0 + 63) inext = t0 + 63;   // dead prefetch -> block-local (L2 hit)
        pring[ss & 15] = P[(size_t)inext * 64 + pidx];
        float term = __builtin_amdgcn_exp2f((vP + num + (tht - den_full)) * LOG2E);
        float mg = dpp_sum64(term);
        mres = (l == ss) ? mg : mres;
        Dcur = Dnext;
    }
    g_mask[(size_t)m * NCOLS + t0 + l] = acc0;               // coalesced 512B
    g_mask[(size_t)(NROWS + m) * NCOLS + t0 + l] = acc1;
    size_t obase = (size_t)2 * 64 * NCOLS * 2;
    out[obase + ((size_t)(m >> 1) * NCOLS + (t0 + l)) * 2 + (m & 1)] = mres;

    // ---- fused scanA: walk both ensembles' maps; ALSO record each entry's
    // full inc-vector so scanC needs no re-walk.
    unsigned int a0lo = (unsigned int)acc0, a0hi = (unsigned int)(acc0 >> 32);
    unsigned int a1lo = (unsigned int)acc1, a1hi = (unsigned int)(acc1 >> 32);
    int r0 = l + 1, r1 = l + 1;              // entry state for this lane
    unsigned long long bits0 = 0, bits1 = 0;
    #pragma unroll
    for (int ss = 0; ss < 64; ++ss) {
        unsigned int m0lo = (unsigned int)__builtin_amdgcn_readlane((int)a0lo, ss);
        unsigned int m0hi = (unsigned int)__builtin_amdgcn_readlane((int)a0hi, ss);
        unsigned int m1lo = (unsigned int)__builtin_amdgcn_readlane((int)a1lo, ss);
        unsigned int m1hi = (unsigned int)__builtin_amdgcn_readlane((int)a1hi, ss);
        unsigned long long msk0 = ((unsigned long long)m0hi << 32) | m0lo;
        unsigned long long msk1 = ((unsigned long long)m1hi << 32) | m1lo;
        int inc0 = (r0 > 0) ? (int)((msk0 >> (r0 - 1)) & 1ULL) : 0;
        int inc1 = (r1 > 0) ? (int)((msk1 >> (r1 - 1)) & 1ULL) : 0;
        bits0 |= ((unsigned long long)inc0) << ss;
        bits1 |= ((unsigned long long)inc1) << ss;
        r0 -= inc0;
        r1 -= inc1;
    }
    g_map[((size_t)m * 64 + b) * 64 + l] = (unsigned char)r0;
    g_map[((size_t)(NROWS + m) * 64 + b) * 64 + l] = (unsigned char)r1;
    g_incs[((size_t)m * 64 + b) * 64 + l] = bits0;
    g_incs[((size_t)(NROWS + m) * 64 + b) * 64 + l] = bits1;
}

// ---- scan phase B: compose the 64 block maps per chain (lane = chain).
__global__ __launch_bounds__(256) void scanB_kernel() {
    int c = threadIdx.x;                     // 0..255, single block
    int r = KVAL;
    for (int b = 0; b < 64; ++b) {
        g_entry[(size_t)c * 64 + b] = (unsigned char)r;
        int idx = (r > 0) ? (r - 1) : 0;     // guard: no g_map[-1] read
        int nxt = g_map[((size_t)c * 64 + b) * 64 + idx];
        r = (r > 0) ? nxt : 0;
    }
}

// ---- scan phase C: read the precomputed inc-vector for the known entry
// state and expand to floats (no re-walk; integer-exact by construction).
__global__ __launch_bounds__(256) void scanC_kernel(float* __restrict__ out) {
    int l = threadIdx.x & 63;
    int wid = threadIdx.x >> 6;
    int unit = blockIdx.x * 4 + wid;         // 0..16383
    int c = unit >> 6;
    int b = unit & 63;
    int tens = c >> 7;
    int m = c & (NROWS - 1);
    float* __restrict__ orow = out + (((size_t)tens * 64 + (m >> 1)) * NCOLS) * 2 + (m & 1);

    int r = g_entry[(size_t)c * 64 + b];     // uniform
    unsigned long long incvec = (r > 0)
        ? g_incs[((size_t)c * 64 + b) * 64 + (r - 1)] : 0ULL;   // uniform
    orow[(size_t)(b * 64 + l) * 2] = (float)((incvec >> l) & 1ULL);
}

extern "C" void kernel_launch(void* const* d_in, const int* in_sizes, int n_in,
                              void* d_out, int out_size, void* d_ws, size_t ws_size,
                              hipStream_t stream) {
    const float* scores = (const float*)d_in[0];   // (64, 4096, 2) f32
    const float* u      = (const float*)d_in[1];   // (2, 128, 4096) f32
    float* out = (float*)d_out;

    dp_kernel<<<2 * NROWS, 64, 0, stream>>>(scores);
    maskA_kernel<<<2048, 256, 0, stream>>>(scores, u, out);
    scanB_kernel<<<1, 256, 0, stream>>>();
    scanC_kernel<<<4096, 256, 0, stream>>>(out);
}

// Round 18
// 219.261 us; speedup vs baseline: 2.2139x; 1.0992x over previous
//
#include <hip/hip_runtime.h>
#include <hip/hip_bf16.h>

#define NROWS 128           // B*E rows
#define NCOLS 4096          // N
#define KVAL  64
#define NEGV  (-1e30f)
#define LOG2E 1.4426950408889634f
#define LN2   0.6931471805599453f

// ESP tables, j=0 column (identically 0) NOT stored: slot j-1 holds state j.
__device__ float g_suf[(size_t)NROWS * (NCOLS + 1) * 64];
__device__ float g_pre[(size_t)NROWS * (NCOLS + 1) * 64];
__device__ unsigned char g_map [(size_t)2 * NROWS * 64 * 64];      // [chain][entry-1][blk]
__device__ unsigned long long g_incs[(size_t)2 * NROWS * 64 * 64]; // [chain][blk][entry-1]

// wave-wide shift-up-by-1 via DPP wave_shr:1 (0x138); lane 0 -> 0.0f.
__device__ __forceinline__ float shr1z(float x) {
    int r = __builtin_amdgcn_update_dpp(0, __float_as_int(x), 0x138, 0xF, 0xF, true);
    return __int_as_float(r);
}
__device__ __forceinline__ float readlane_f(float v, int lane) {
    return __int_as_float(__builtin_amdgcn_readlane(__float_as_int(v), lane));
}
// fast logaddexp: max(a,b) + ln2 * log2(1 + exp2(-|a-b|*log2e))
// (bit-identical to rounds 3..17 passing table construction)
__device__ __forceinline__ float lae_fast(float a, float b) {
    float mx = fmaxf(a, b);
    float d  = fabsf(a - b);
    float e  = __builtin_amdgcn_exp2f(d * -LOG2E);
    return fmaf(__builtin_amdgcn_logf(1.0f + e), LN2, mx);
}

// DPP wave64 sum reduction (VALU pipe; result broadcast from lane 63).
__device__ __forceinline__ float dpp_sum64(float x) {
#define SSTEP(ctrl, rmask) { int t_ = __builtin_amdgcn_update_dpp(0, \
        __float_as_int(x), ctrl, rmask, 0xF, false); x = x + __int_as_float(t_); }
    SSTEP(0x111, 0xF) SSTEP(0x112, 0xF) SSTEP(0x114, 0xF) SSTEP(0x118, 0xF)
    SSTEP(0x142, 0xA) SSTEP(0x143, 0xC)
#undef SSTEP
    return readlane_f(x, 63);
}

// DP, round-11/17 carry chain (bit-identical); theta tiles loaded directly
// from scores (stride-8B coalesced, off-chain). Structural floor: 4096
// sequential steps x ~88cy (2 TRANS + 6 VALU dependent + DPP) ~= 150us.
__global__ __launch_bounds__(64, 1) void dp_kernel(const float* __restrict__ scores) {
    int blk = blockIdx.x;
    int l = threadIdx.x;
    bool suf = (blk < NROWS);
    int m = suf ? blk : (blk - NROWS);
    float* __restrict__ tab = (suf ? g_suf : g_pre) + (size_t)m * (NCOLS + 1) * 64;
    const float* __restrict__ srow = scores + (size_t)(m >> 1) * (NCOLS * 2) + (m & 1);

    tab[(size_t)(suf ? NCOLS : 0) * 64 + l] = NEGV;    // init state row
    float s = NEGV;
    if (suf) {
        float tile = srow[(size_t)(NCOLS - 64 + l) * 2];       // theta tile
        for (int t0 = NCOLS - 64; t0 >= 0; t0 -= 64) {
            float nxt = (t0 >= 64) ? srow[(size_t)(t0 - 64 + l) * 2] : 0.0f;
            #pragma unroll
            for (int ss = 63; ss >= 0; --ss) {
                float tht = readlane_f(tile, ss);      // broadcast, off-chain
                float b = shr1z(s) + tht;
                s = lae_fast(s, b);
                tab[(size_t)(t0 + ss) * 64 + l] = s;
            }
            tile = nxt;
        }
    } else {
        float tile = srow[(size_t)l * 2];
        for (int t0 = 0; t0 < NCOLS; t0 += 64) {
            float nxt = (t0 + 64 < NCOLS) ? srow[(size_t)(t0 + 64 + l) * 2] : 0.0f;
            #pragma unroll
            for (int ss = 0; ss < 64; ++ss) {
                float tht = readlane_f(tile, ss);
                float b = shr1z(s) + tht;
                s = lae_fast(s, b);
                tab[(size_t)(t0 + ss + 1) * 64 + l] = s;
            }
            tile = nxt;
        }
    }
}

// Fused: sampler masks + scanA (+inc vectors) + marginals.
// Round-17 float paths bit-for-bit. Changes: g_mask stores DELETED (write-only
// since round 15); transition map written TRANSPOSED [chain][entry][blk] for
// the register-resident compose in scanBC.
__global__ __launch_bounds__(256) void maskA_kernel(const float* __restrict__ scores,
                                                    const float* __restrict__ u,
                                                    float* __restrict__ out) {
    int l = threadIdx.x & 63;
    int wid = threadIdx.x >> 6;
    int unit = blockIdx.x * 4 + wid;         // 0..8191
    int m  = unit >> 6;
    int b  = unit & 63;                      // t-block index
    int t0 = b << 6;
    size_t rowbase = (size_t)m * (NCOLS + 1) * 64;
    const float* __restrict__ S = g_suf + rowbase;
    const float* __restrict__ P = g_pre + rowbase;
    const float* __restrict__ srow = scores + (size_t)(m >> 1) * (NCOLS * 2) + (m & 1);
    const float* __restrict__ u0 = u + (size_t)m * NCOLS;             // ens 0
    const float* __restrict__ u1 = u + (size_t)(NROWS + m) * NCOLS;   // ens 1

    // register tiles: lane l holds step t0+l's theta/u values
    float thtile = srow[(size_t)(t0 + l) * 2];
    float u0tile = u0[t0 + l];
    float u1tile = u1[t0 + l];

    float den_full = P[(size_t)NCOLS * 64 + 63];     // log E_k(full row), uniform

    // P-row prefetch ring: lane l reads P[i][62-l] (l=63 reads slot 62, masked).
    int pidx = (l < 63) ? (62 - l) : 62;
    float pring[16];
    #pragma unroll
    for (int j = 0; j < 16; ++j)
        pring[j] = P[(size_t)(t0 + j) * 64 + pidx];

    // S-row ring: den carried in Dcur; ring holds rows t0+1 .. t0+16.
    float Dcur = S[(size_t)t0 * 64 + l];
    float sring[16];
    #pragma unroll
    for (int j = 0; j < 16; ++j)
        sring[j] = S[(size_t)(t0 + 1 + j) * 64 + l];

    unsigned long long acc0 = 0, acc1 = 0;   // lane ss <- masks of step t0+ss
    float mres = 0.0f;                       // lane ss <- marg of element t0+ss
    #pragma unroll
    for (int ss = 0; ss < 64; ++ss) {
        int t = t0 + ss;
        float Dnext = sring[ss & 15];        // S row t+1
        int snext = t0 + ss + 17;
        if (snext > t0 + 64) snext = t0 + 64;   // dead prefetch -> block-local (L2 hit)
        sring[ss & 15] = S[(size_t)snext * 64 + l];
        // ---- sampler mask (expression identical to passing round-17 kernel)
        float num = shr1z(Dnext);            // row t+1, state l (lane0 -> 0)
        float den = Dcur;                    // row t, state l+1
        float tht = readlane_f(thtile, ss);
        float uu0 = readlane_f(u0tile, ss);
        float uu1 = readlane_f(u1tile, ss);
        float p = __builtin_amdgcn_exp2f(((num + tht) - den) * LOG2E);
        unsigned long long b0 = __ballot(uu0 < p);
        unsigned long long b1 = __ballot(uu1 < p);
        acc0 = (l == ss) ? b0 : acc0;
        acc1 = (l == ss) ? b1 : acc1;
        // ---- marginal (output 1): S-side term is exactly `num`; P from ring.
        float vP = (l == 63) ? 0.0f : pring[ss & 15];
        int inext = t + 16;
        if (inext > t0 + 63) inext = t0 + 63;   // dead prefetch -> block-local (L2 hit)
        pring[ss & 15] = P[(size_t)inext * 64 + pidx];
        float term = __builtin_amdgcn_exp2f((vP + num + (tht - den_full)) * LOG2E);
        float mg = dpp_sum64(term);
        mres = (l == ss) ? mg : mres;
        Dcur = Dnext;
    }
    size_t obase = (size_t)2 * 64 * NCOLS * 2;
    out[obase + ((size_t)(m >> 1) * NCOLS + (t0 + l)) * 2 + (m & 1)] = mres;

    // ---- fused scanA: walk both ensembles' maps from registers; record each
    // entry's full inc-vector so the final pass needs no re-walk.
    unsigned int a0lo = (unsigned int)acc0, a0hi = (unsigned int)(acc0 >> 32);
    unsigned int a1lo = (unsigned int)acc1, a1hi = (unsigned int)(acc1 >> 32);
    int r0 = l + 1, r1 = l + 1;              // entry state for this lane
    unsigned long long bits0 = 0, bits1 = 0;
    #pragma unroll
    for (int ss = 0; ss < 64; ++ss) {
        unsigned int m0lo = (unsigned int)__builtin_amdgcn_readlane((int)a0lo, ss);
        unsigned int m0hi = (unsigned int)__builtin_amdgcn_readlane((int)a0hi, ss);
        unsigned int m1lo = (unsigned int)__builtin_amdgcn_readlane((int)a1lo, ss);
        unsigned int m1hi = (unsigned int)__builtin_amdgcn_readlane((int)a1hi, ss);
        unsigned long long msk0 = ((unsigned long long)m0hi << 32) | m0lo;
        unsigned long long msk1 = ((unsigned long long)m1hi << 32) | m1lo;
        int inc0 = (r0 > 0) ? (int)((msk0 >> (r0 - 1)) & 1ULL) : 0;
        int inc1 = (r1 > 0) ? (int)((msk1 >> (r1 - 1)) & 1ULL) : 0;
        bits0 |= ((unsigned long long)inc0) << ss;
        bits1 |= ((unsigned long long)inc1) << ss;
        r0 -= inc0;
        r1 -= inc1;
    }
    // transposed map: [chain][entry-1 = l][blk = b]
    g_map[(size_t)m * 4096 + (size_t)l * 64 + b] = (unsigned char)r0;
    g_map[(size_t)(NROWS + m) * 4096 + (size_t)l * 64 + b] = (unsigned char)r1;
    g_incs[((size_t)m * 64 + b) * 64 + l] = bits0;
    g_incs[((size_t)(NROWS + m) * 64 + b) * 64 + l] = bits1;
}

// ---- scanBC: one wave per chain. Loads the chain's 4KB transition map into
// registers (lane l = row for entry l+1, 16 dwords), composes the 64 block
// maps in-register (readlane: register index is a literal under full unroll,
// lane index is the uniform running state), gathers each block's inc-vector
// with ONE per-lane load, then emits output via 64 broadcast+bit-extract
// stores. Integer-exact: same compose recurrence as the round-17 scanB/scanC.
__global__ __launch_bounds__(64) void scanBC_kernel(float* __restrict__ out) {
    int c = blockIdx.x;                  // 0..255
    int l = threadIdx.x;
    int tens = c >> 7;
    int m = c & (NROWS - 1);
    float* __restrict__ orow = out + (((size_t)tens * 64 + (m >> 1)) * NCOLS) * 2 + (m & 1);

    // load row l of the transposed map: value[b] = end-state of block b from entry l+1
    const uint4* __restrict__ vp =
        (const uint4*)(g_map + (size_t)c * 4096 + (size_t)l * 64);
    unsigned int v[16];
    {
        uint4 q0 = vp[0], q1 = vp[1], q2 = vp[2], q3 = vp[3];
        v[0]=q0.x; v[1]=q0.y; v[2]=q0.z; v[3]=q0.w;
        v[4]=q1.x; v[5]=q1.y; v[6]=q1.z; v[7]=q1.w;
        v[8]=q2.x; v[9]=q2.y; v[10]=q2.z; v[11]=q2.w;
        v[12]=q3.x; v[13]=q3.y; v[14]=q3.z; v[15]=q3.w;
    }

    // compose: r_{b+1} = (r_b > 0) ? map[b][r_b - 1] : 0 ; record rvec[lane b] = r_b
    int r = KVAL;
    int rvec = 0;
    #pragma unroll
    for (int b = 0; b < 64; ++b) {
        rvec = (l == b) ? r : rvec;                     // entry state of block b
        int safe = (r > 0) ? (r - 1) : 0;               // uniform lane index
        unsigned int word = (unsigned int)__builtin_amdgcn_readlane((int)v[b >> 2], safe);
        int nxt = (int)((word >> ((b & 3) * 8)) & 0xFFu);
        r = (r > 0) ? nxt : 0;
    }

    // gather this block's inc-vector for its entry state (one load per lane)
    int e = (rvec > 0) ? (rvec - 1) : 0;
    unsigned long long iv = g_incs[((size_t)c * 64 + l) * 64 + e];
    if (rvec == 0) iv = 0ULL;
    unsigned int ivlo = (unsigned int)iv, ivhi = (unsigned int)(iv >> 32);

    // emit: step b broadcasts block b's vector; lane l writes bit l (t = b*64+l)
    #pragma unroll
    for (int b = 0; b < 64; ++b) {
        unsigned int lo = (unsigned int)__builtin_amdgcn_readlane((int)ivlo, b);
        unsigned int hi = (unsigned int)__builtin_amdgcn_readlane((int)ivhi, b);
        unsigned long long vec = ((unsigned long long)hi << 32) | lo;
        orow[(size_t)(b * 64 + l) * 2] = (float)((vec >> l) & 1ULL);
    }
}

extern "C" void kernel_launch(void* const* d_in, const int* in_sizes, int n_in,
                              void* d_out, int out_size, void* d_ws, size_t ws_size,
                              hipStream_t stream) {
    const float* scores = (const float*)d_in[0];   // (64, 4096, 2) f32
    const float* u      = (const float*)d_in[1];   // (2, 128, 4096) f32
    float* out = (float*)d_out;

    dp_kernel<<<2 * NROWS, 64, 0, stream>>>(scores);
    maskA_kernel<<<2048, 256, 0, stream>>>(scores, u, out);
    scanBC_kernel<<<2 * NROWS, 64, 0, stream>>>(out);
}